// Round 4
// baseline (525.394 us; speedup 1.0000x reference)
//
#include <hip/hip_runtime.h>
#include <hip/hip_bf16.h>

#define T_ 4
#define C_ 64
#define H_ 128
#define W_ 128
#define CI_ 16
#define PS_ 7
#define NC_ 729       // 27*27 candidates per query
#define S0_ 4
#define KS_ 100
#define NQ_ 1024      // 32*32 queries per frame
#define SCALE_ 10.0f
#define HW_ (H_*W_)
#define RW_ 37        // region dim (float4); odd -> bank-quad rotation 5/row
#define LCAP_ 768

// ---------------- conv 3x3, 64->16, pad=1 (zero), chunk-major float4 output ----
// Block = 16x16 spatial tile; LDS-staged 18x18 input tile per 4-channel chunk;
// weights via wave-uniform global reads (compiler scalarizes to s_load).
__global__ __launch_bounds__(256) void conv3x3_kernel(
    const float* __restrict__ vid, const float* __restrict__ gw,
    const float* __restrict__ gb, float4* __restrict__ v1cs) {
  __shared__ float4 tileS[18 * 19];   // stride 19 (odd) to spread banks
  const int tid = threadIdx.x;
  const int t = blockIdx.y;
  const int ti0 = (blockIdx.x >> 3) * 16, tj0 = (blockIdx.x & 7) * 16;
  const int u = tid >> 4, v = tid & 15;
  float acc[16];
#pragma unroll
  for (int co = 0; co < 16; ++co) acc[co] = gb[co];
#pragma unroll 1
  for (int cc = 0; cc < 16; ++cc) {
    __syncthreads();
    const float* vb = vid + ((size_t)(t * C_ + cc * 4)) * HW_;
    for (int p = tid; p < 324; p += 256) {
      int uu = p / 18, vv = p - uu * 18;
      int gi = ti0 + uu - 1, gj = tj0 + vv - 1;
      float4 val = make_float4(0.f, 0.f, 0.f, 0.f);
      if (gi >= 0 && gi < H_ && gj >= 0 && gj < W_) {
        int o = gi * W_ + gj;
        val.x = vb[o]; val.y = vb[HW_ + o]; val.z = vb[2 * HW_ + o]; val.w = vb[3 * HW_ + o];
      }
      tileS[uu * 19 + vv] = val;
    }
    __syncthreads();
    float4 n[9];
#pragma unroll
    for (int ki = 0; ki < 3; ++ki)
#pragma unroll
      for (int kj = 0; kj < 3; ++kj)
        n[ki * 3 + kj] = tileS[(u + ki) * 19 + v + kj];
#pragma unroll
    for (int co = 0; co < 16; ++co) {
      const float* wc = gw + ((size_t)co * C_ + cc * 4) * 9;
#pragma unroll
      for (int k = 0; k < 9; ++k) {
        acc[co] = fmaf(wc[k],      n[k].x, acc[co]);
        acc[co] = fmaf(wc[9 + k],  n[k].y, acc[co]);
        acc[co] = fmaf(wc[18 + k], n[k].z, acc[co]);
        acc[co] = fmaf(wc[27 + k], n[k].w, acc[co]);
      }
    }
  }
  const int pix = (ti0 + u) * W_ + tj0 + v;
#pragma unroll
  for (int g = 0; g < 4; ++g)
    v1cs[((size_t)g * T_ + t) * HW_ + pix] =
        make_float4(acc[4 * g], acc[4 * g + 1], acc[4 * g + 2], acc[4 * g + 3]);
}

// ---------------- conv 1x1, 64->16, chunk-major float4 output ----------------
__global__ __launch_bounds__(256) void conv1x1_kernel(
    const float* __restrict__ vid, const float* __restrict__ tw,
    const float* __restrict__ tb, float4* __restrict__ v2cs) {
  __shared__ float w[C_ * CI_];   // w[c*16 + o]
  const int t = blockIdx.y;
  for (int m = threadIdx.x; m < C_ * CI_; m += 256) {
    int o = m & 15, c = m >> 4;
    w[m] = tw[o * C_ + c];
  }
  __syncthreads();
  const int pix = blockIdx.x * 256 + threadIdx.x;
  float acc[CI_];
#pragma unroll
  for (int o = 0; o < CI_; ++o) acc[o] = tb[o];
  for (int c = 0; c < C_; ++c) {
    float x = vid[((size_t)(t * C_ + c)) * HW_ + pix];
#pragma unroll
    for (int o = 0; o < CI_; ++o) acc[o] = fmaf(w[c * 16 + o], x, acc[o]);
  }
#pragma unroll
  for (int cc = 0; cc < 4; ++cc)
    v2cs[((size_t)cc * T_ + t) * HW_ + pix] =
        make_float4(acc[cc * 4], acc[cc * 4 + 1], acc[cc * 4 + 2], acc[cc * 4 + 3]);
}

// ---------------- Zc: fold counts ----------------
__global__ void zc_kernel(float* __restrict__ Zc) {
  int idx = blockIdx.x * blockDim.x + threadIdx.x;
  if (idx >= NQ_ * PS_ * PS_) return;
  int q = idx / 49, rs = idx - q * 49;
  int qi = (q >> 5) * S0_, qj = (q & 31) * S0_;
  int r = rs / 7, s = rs - r * 7;
  atomicAdd(&Zc[min(qi + r, H_ - 1) * W_ + min(qj + s, W_ - 1)], 1.0f);
}

// ---------------- dists: 2x2-query-tile region, wave=query, j=14/lane ------
// Block 256 = 4 waves; block covers queries (qi0+{0,4}, qj0+{0,4}) sharing a
// 37x37 float4 region (stride 37, odd -> conflict-free at b128 floor).
// Lane: ai=lane>>1 (cand row, clamped-dup), bg=lane&1 (col group: b_lo or 13),
// 14 candidates/lane via compile-time triangular sliding window.
__global__ __launch_bounds__(256, 4) void dist_kernel(
    const float4* __restrict__ v1cs, float* __restrict__ distG) {
  __shared__ float4 Rs[RW_ * RW_];
  const int tid = threadIdx.x;
  const int t = blockIdx.y;
  const int qi0 = (blockIdx.x >> 4) * 8, qj0 = (blockIdx.x & 15) * 8;
  const int w = tid >> 6, lane = tid & 63;
  const int di = (w >> 1) * 4, dj = (w & 1) * 4;
  const int qi = qi0 + di, qj = qj0 + dj;
  const int a_lo = max(13 - qi, 0), b_lo = max(13 - qj, 0);
  const int ai = lane >> 1, bg = lane & 1;
  const bool active = ai < 27;
  const int a = min(a_lo + ai, 26);
  const int bs = bg ? 13 : b_lo;

  float4 acc[14];
#pragma unroll
  for (int j = 0; j < 14; ++j) acc[j] = make_float4(0.f, 0.f, 0.f, 0.f);

#pragma unroll 1
  for (int cc = 0; cc < 4; ++cc) {
    __syncthreads();
    const float4* src = v1cs + ((size_t)cc * T_ + t) * HW_;
    for (int p = tid; p < RW_ * RW_; p += 256) {
      int uu = p / RW_, vv = p - uu * RW_;
      int row = min(max(qi0 - 13 + uu, 0), H_ - 1);
      int col = min(max(qj0 - 13 + vv, 0), W_ - 1);
      Rs[p] = src[row * W_ + col];
    }
    __syncthreads();
    if (active) {
#pragma unroll 1
      for (int r = 0; r < 7; ++r) {
        float4 qv[7];
        const float4* qrow = &Rs[(di + 13 + r) * RW_ + dj + 13];
#pragma unroll
        for (int s = 0; s < 7; ++s) qv[s] = qrow[s];
        const float4* crow = &Rs[(di + a + r) * RW_ + dj + bs];
#pragma unroll
        for (int y = 0; y < 20; ++y) {
          float4 vv = crow[y];
          const int s_lo = (y > 13) ? (y - 13) : 0;
          const int s_hi = (y < 6) ? y : 6;
#pragma unroll
          for (int s = s_lo; s <= s_hi; ++s) {
            float4 qq = qv[s];
            int j = y - s;
            acc[j].x = fmaf(qq.x, vv.x, acc[j].x);
            acc[j].y = fmaf(qq.y, vv.y, acc[j].y);
            acc[j].z = fmaf(qq.z, vv.z, acc[j].z);
            acc[j].w = fmaf(qq.w, vv.w, acc[j].w);
          }
        }
      }
    }
  }
  if (active) {
    const int q = ((qi >> 2) << 5) + (qj >> 2);
    float* out = distG + ((size_t)t * NQ_ + q) * NC_ + a * 27 + bs;
#pragma unroll
    for (int j = 0; j < 14; ++j)
      out[j] = (acc[j].x + acc[j].y) + (acc[j].z + acc[j].w);
  }
}

// ---------------- select: histogram top-100 + exact tie-break + softmax -----
__global__ __launch_bounds__(256) void select_kernel(
    const float* __restrict__ distG, int* __restrict__ sel_n,
    float* __restrict__ sel_w, float* __restrict__ wsum_out) {
  __shared__ float dist[NC_];
  __shared__ unsigned int ukey[NC_];
  __shared__ float red[256];
  __shared__ unsigned int hist[256];
  __shared__ int sfx[64];
  __shared__ int lk[LCAP_];
  __shared__ unsigned int lkey[LCAP_];
  __shared__ unsigned int scal[4];   // 0=beta 1=run 2=out cursor 3=list len

  const int tid = threadIdx.x;
  const int q = blockIdx.x, t = blockIdx.y;
  const int qi = (q >> 5) * S0_, qj = (q & 31) * S0_;
  const int a_lo = max(13 - qi, 0), b_lo = max(13 - qj, 0);
  const size_t base = ((size_t)t * NQ_ + q) * NC_;

  for (int h = tid; h < 256; h += 256) hist[h] = 0;
  if (tid == 0) { scal[2] = 0; scal[3] = 0; }
  for (int k = tid; k < NC_; k += 256) {
    int aa = k / 27, bb = k - aa * 27;
    int kk = max(aa, a_lo) * 27 + max(bb, b_lo);
    float d = distG[base + kk];
    dist[k] = d;
    unsigned int u = __float_as_uint(d);
    ukey[k] = u ^ (((unsigned int)((int)u >> 31)) | 0x80000000u);
  }
  __syncthreads();
  float lmax = -INFINITY;
  for (int k = tid; k < NC_; k += 256) lmax = fmaxf(lmax, dist[k]);
  red[tid] = lmax;
  __syncthreads();
  for (int off = 128; off > 0; off >>= 1) {
    if (tid < off) red[tid] = fmaxf(red[tid], red[tid + off]);
    __syncthreads();
  }
  const float dmax = red[0];
  __syncthreads();
  for (int k = tid; k < NC_; k += 256) atomicAdd(&hist[ukey[k] >> 24], 1u);
  __syncthreads();
  if (tid < 64)
    sfx[tid] = (int)(hist[tid * 4] + hist[tid * 4 + 1] + hist[tid * 4 + 2] + hist[tid * 4 + 3]);
  __syncthreads();
  for (int off = 1; off < 64; off <<= 1) {
    int v = 0;
    if (tid < 64 && tid + off < 64) v = sfx[tid + off];
    __syncthreads();
    if (tid < 64) sfx[tid] += v;
    __syncthreads();
  }
  if (tid < 64) {
    int s4 = (int)(hist[tid * 4] + hist[tid * 4 + 1] + hist[tid * 4 + 2] + hist[tid * 4 + 3]);
    int above = sfx[tid] - s4;
    if (above < KS_ && sfx[tid] >= KS_) {
      int run = above;
#pragma unroll
      for (int bb = 3; bb >= 0; --bb) {
        int h = (int)hist[tid * 4 + bb];
        if (run + h >= KS_) { scal[0] = (unsigned int)(tid * 4 + bb); scal[1] = (unsigned int)run; break; }
        run += h;
      }
    }
  }
  __syncthreads();
  const unsigned int beta = scal[0];
  const int run = (int)scal[1];
  const size_t outb = ((size_t)t * NQ_ + q) * KS_;
  float lsum = 0.f;
  for (int k = tid; k < NC_; k += 256) {
    unsigned int key = ukey[k];
    unsigned int bin = key >> 24;
    if (bin > beta) {
      unsigned int slot = atomicAdd(&scal[2], 1u);
      int aa = k / 27, bb = k - aa * 27;
      int ni = min(max(qi + aa - 13, 0), H_ - 1);
      int nj = min(max(qj + bb - 13, 0), W_ - 1);
      float wv = __expf(SCALE_ * (dist[k] - dmax));
      sel_n[outb + slot] = (ni << 7) | nj;
      sel_w[outb + slot] = wv;
      lsum += wv;
    } else if (bin == beta) {
      unsigned int pos = atomicAdd(&scal[3], 1u);
      if (pos < LCAP_) { lk[pos] = k; lkey[pos] = key; }
    }
  }
  __syncthreads();
  const int L = min((int)scal[3], LCAP_);
  for (int i = tid; i < L; i += 256) {
    unsigned int key = lkey[i];
    int k = lk[i];
    int cnt = run;
    for (int m = 0; m < L; ++m)
      cnt += (int)((lkey[m] > key) || (lkey[m] == key && lk[m] < k));
    if (cnt < KS_) {
      unsigned int slot = atomicAdd(&scal[2], 1u);
      int aa = k / 27, bb = k - aa * 27;
      int ni = min(max(qi + aa - 13, 0), H_ - 1);
      int nj = min(max(qj + bb - 13, 0), W_ - 1);
      float wv = __expf(SCALE_ * (dist[k] - dmax));
      sel_n[outb + slot] = (ni << 7) | nj;
      sel_w[outb + slot] = wv;
      lsum += wv;
    }
  }
  __syncthreads();
  red[tid] = lsum;
  __syncthreads();
  for (int off = 128; off > 0; off >>= 1) {
    if (tid < off) red[tid] += red[tid + off];
    __syncthreads();
  }
  if (tid == 0) wsum_out[t * NQ_ + q] = red[0];
}

// ---------------- weighted aggregation + fold (2x2-tile region) -------------
__global__ __launch_bounds__(256) void agg_kernel(
    const float4* __restrict__ v2cs, const int* __restrict__ sel_n,
    const float* __restrict__ sel_w, const float* __restrict__ wsum,
    float* __restrict__ Y) {
  __shared__ float4 Rs[RW_ * RW_];
  __shared__ int s_off[4][KS_];
  __shared__ float s_w[4][KS_];
  const int tid = threadIdx.x;
  const int t = blockIdx.y;
  const int qi0 = (blockIdx.x >> 4) * 8, qj0 = (blockIdx.x & 15) * 8;
  const int w = tid >> 6, lane = tid & 63;
  const int di = (w >> 1) * 4, dj = (w & 1) * 4;
  const int qi = qi0 + di, qj = qj0 + dj;
  const int q = ((qi >> 2) << 5) + (qj >> 2);
  const size_t base = ((size_t)t * NQ_ + q) * KS_;
  const float inv = 1.0f / wsum[t * NQ_ + q];
  for (int k = lane; k < KS_; k += 64) {
    int n = sel_n[base + k];
    int ni = n >> 7, nj = n & 127;
    s_off[w][k] = (ni - qi0 + 13) * RW_ + (nj - qj0 + 13);
    s_w[w][k] = sel_w[base + k] * inv;
  }
  const int r = lane / 7, s = lane - r * 7;   // valid for lane < 49
  const int myo = r * RW_ + s;
#pragma unroll 1
  for (int cc = 0; cc < 4; ++cc) {
    __syncthreads();
    const float4* src = v2cs + ((size_t)cc * T_ + t) * HW_;
    for (int p = tid; p < RW_ * RW_; p += 256) {
      int uu = p / RW_, vv = p - uu * RW_;
      int row = min(max(qi0 - 13 + uu, 0), H_ - 1);
      int col = min(max(qj0 - 13 + vv, 0), W_ - 1);
      Rs[p] = src[row * W_ + col];
    }
    __syncthreads();
    if (lane < 49) {
      float4 acc = make_float4(0.f, 0.f, 0.f, 0.f);
#pragma unroll 4
      for (int k = 0; k < KS_; ++k) {
        float wv = s_w[w][k];
        float4 v = Rs[s_off[w][k] + myo];
        acc.x = fmaf(wv, v.x, acc.x);
        acc.y = fmaf(wv, v.y, acc.y);
        acc.z = fmaf(wv, v.z, acc.z);
        acc.w = fmaf(wv, v.w, acc.w);
      }
      const int oi = min(qi + r, H_ - 1), oj = min(qj + s, W_ - 1);
      float* yb = Y + (((size_t)t * CI_ + cc * 4) * H_ + oi) * W_ + oj;
      atomicAdd(yb, acc.x);
      atomicAdd(yb + HW_, acc.y);
      atomicAdd(yb + 2 * HW_, acc.z);
      atomicAdd(yb + 3 * HW_, acc.w);
    }
  }
}

// ---------------- normalize by fold counts ----------------
__global__ void norm_kernel(float* __restrict__ Y, const float* __restrict__ Zc) {
  int idx = blockIdx.x * blockDim.x + threadIdx.x;
  if (idx >= T_ * CI_ * HW_) return;
  Y[idx] /= Zc[idx & (HW_ - 1)];
}

extern "C" void kernel_launch(void* const* d_in, const int* in_sizes, int n_in,
                              void* d_out, int out_size, void* d_ws, size_t ws_size,
                              hipStream_t stream) {
  const float* vid     = (const float*)d_in[0];
  const float* g_w     = (const float*)d_in[1];
  const float* g_b     = (const float*)d_in[2];
  const float* theta_w = (const float*)d_in[3];
  const float* theta_b = (const float*)d_in[4];
  float* Y = (float*)d_out;

  // workspace (floats): v1cs | v2cs | distG | sel_n | sel_w | wsum | Zc  (~24 MB)
  float* v1cs  = (float*)d_ws;
  float* v2cs  = v1cs + (size_t)4 * T_ * HW_ * 4;              // 1048576
  float* distG = v2cs + (size_t)4 * T_ * HW_ * 4;              // 1048576
  int*   sel_n = (int*)(distG + (size_t)T_ * NQ_ * NC_);       // 2985984
  float* sel_w = (float*)(sel_n + (size_t)T_ * NQ_ * KS_);     // 409600
  float* wsumv = sel_w + (size_t)T_ * NQ_ * KS_;               // 409600
  float* Zc    = wsumv + (size_t)T_ * NQ_;                     // 4096

  hipMemsetAsync(Y, 0, (size_t)out_size * sizeof(float), stream);
  hipMemsetAsync(Zc, 0, (size_t)HW_ * sizeof(float), stream);

  conv3x3_kernel<<<dim3(64, T_), 256, 0, stream>>>(vid, g_w, g_b, (float4*)v1cs);
  conv1x1_kernel<<<dim3(HW_ / 256, T_), 256, 0, stream>>>(vid, theta_w, theta_b, (float4*)v2cs);
  zc_kernel<<<(NQ_ * PS_ * PS_ + 255) / 256, 256, 0, stream>>>(Zc);
  dist_kernel<<<dim3(256, T_), 256, 0, stream>>>((const float4*)v1cs, distG);
  select_kernel<<<dim3(NQ_, T_), 256, 0, stream>>>(distG, sel_n, sel_w, wsumv);
  agg_kernel<<<dim3(256, T_), 256, 0, stream>>>((const float4*)v2cs, sel_n, sel_w, wsumv, Y);
  norm_kernel<<<(T_ * CI_ * HW_ + 255) / 256, 256, 0, stream>>>(Y, Zc);
}

// Round 5
// 431.895 us; speedup vs baseline: 1.2165x; 1.2165x over previous
//
#include <hip/hip_runtime.h>
#include <hip/hip_bf16.h>

#define T_ 4
#define C_ 64
#define H_ 128
#define W_ 128
#define CI_ 16
#define PS_ 7
#define NC_ 729       // 27*27 candidates per query
#define S0_ 4
#define KS_ 100
#define NQ_ 1024      // 32*32 queries per frame
#define SCALE_ 10.0f
#define HW_ (H_*W_)
#define RW_ 37        // region dim (float4); odd -> bank-quad rotation 5/row
#define LCAP_ 768

// ---------------- conv 3x3, 64->16, pad=1 (zero), chunk-major float4 output ----
__global__ __launch_bounds__(256) void conv3x3_kernel(
    const float* __restrict__ vid, const float* __restrict__ gw,
    const float* __restrict__ gb, float4* __restrict__ v1cs) {
  __shared__ float4 tileS[18 * 19];   // stride 19 (odd) to spread banks
  const int tid = threadIdx.x;
  const int t = blockIdx.y;
  const int ti0 = (blockIdx.x >> 3) * 16, tj0 = (blockIdx.x & 7) * 16;
  const int u = tid >> 4, v = tid & 15;
  float acc[16];
#pragma unroll
  for (int co = 0; co < 16; ++co) acc[co] = gb[co];
#pragma unroll 1
  for (int cc = 0; cc < 16; ++cc) {
    __syncthreads();
    const float* vb = vid + ((size_t)(t * C_ + cc * 4)) * HW_;
    for (int p = tid; p < 324; p += 256) {
      int uu = p / 18, vv = p - uu * 18;
      int gi = ti0 + uu - 1, gj = tj0 + vv - 1;
      float4 val = make_float4(0.f, 0.f, 0.f, 0.f);
      if (gi >= 0 && gi < H_ && gj >= 0 && gj < W_) {
        int o = gi * W_ + gj;
        val.x = vb[o]; val.y = vb[HW_ + o]; val.z = vb[2 * HW_ + o]; val.w = vb[3 * HW_ + o];
      }
      tileS[uu * 19 + vv] = val;
    }
    __syncthreads();
    float4 n[9];
#pragma unroll
    for (int ki = 0; ki < 3; ++ki)
#pragma unroll
      for (int kj = 0; kj < 3; ++kj)
        n[ki * 3 + kj] = tileS[(u + ki) * 19 + v + kj];
#pragma unroll
    for (int co = 0; co < 16; ++co) {
      const float* wc = gw + ((size_t)co * C_ + cc * 4) * 9;
#pragma unroll
      for (int k = 0; k < 9; ++k) {
        acc[co] = fmaf(wc[k],      n[k].x, acc[co]);
        acc[co] = fmaf(wc[9 + k],  n[k].y, acc[co]);
        acc[co] = fmaf(wc[18 + k], n[k].z, acc[co]);
        acc[co] = fmaf(wc[27 + k], n[k].w, acc[co]);
      }
    }
  }
  const int pix = (ti0 + u) * W_ + tj0 + v;
#pragma unroll
  for (int g = 0; g < 4; ++g)
    v1cs[((size_t)g * T_ + t) * HW_ + pix] =
        make_float4(acc[4 * g], acc[4 * g + 1], acc[4 * g + 2], acc[4 * g + 3]);
}

// ---------------- conv 1x1, 64->16, chunk-major float4 output ----------------
__global__ __launch_bounds__(256) void conv1x1_kernel(
    const float* __restrict__ vid, const float* __restrict__ tw,
    const float* __restrict__ tb, float4* __restrict__ v2cs) {
  __shared__ float w[C_ * CI_];   // w[c*16 + o]
  const int t = blockIdx.y;
  for (int m = threadIdx.x; m < C_ * CI_; m += 256) {
    int o = m & 15, c = m >> 4;
    w[m] = tw[o * C_ + c];
  }
  __syncthreads();
  const int pix = blockIdx.x * 256 + threadIdx.x;
  float acc[CI_];
#pragma unroll
  for (int o = 0; o < CI_; ++o) acc[o] = tb[o];
  for (int c = 0; c < C_; ++c) {
    float x = vid[((size_t)(t * C_ + c)) * HW_ + pix];
#pragma unroll
    for (int o = 0; o < CI_; ++o) acc[o] = fmaf(w[c * 16 + o], x, acc[o]);
  }
#pragma unroll
  for (int cc = 0; cc < 4; ++cc)
    v2cs[((size_t)cc * T_ + t) * HW_ + pix] =
        make_float4(acc[cc * 4], acc[cc * 4 + 1], acc[cc * 4 + 2], acc[cc * 4 + 3]);
}

// ---------------- Zc: fold counts ----------------
__global__ void zc_kernel(float* __restrict__ Zc) {
  int idx = blockIdx.x * blockDim.x + threadIdx.x;
  if (idx >= NQ_ * PS_ * PS_) return;
  int q = idx / 49, rs = idx - q * 49;
  int qi = (q >> 5) * S0_, qj = (q & 31) * S0_;
  int r = rs / 7, s = rs - r * 7;
  atomicAdd(&Zc[min(qi + r, H_ - 1) * W_ + min(qj + s, W_ - 1)], 1.0f);
}

// ---------------- dists: 2x2-query-tile region, wave=query, j=14/lane ------
// Block 256 = 4 waves; queries (qi0+{0,4}, qj0+{0,4}) share a 37x37 float4
// region. Lane: ai=lane>>1 (cand row), bg=lane&1 (col group b_lo / 13).
// Scalar f32 accumulators (14) — no spill; vv loaded per-y from LDS.
__global__ __launch_bounds__(256) void dist_kernel(
    const float4* __restrict__ v1cs, float* __restrict__ distG) {
  __shared__ float4 Rs[RW_ * RW_];
  const int tid = threadIdx.x;
  const int t = blockIdx.y;
  const int qi0 = (blockIdx.x >> 4) * 8, qj0 = (blockIdx.x & 15) * 8;
  const int w = tid >> 6, lane = tid & 63;
  const int di = (w >> 1) * 4, dj = (w & 1) * 4;
  const int qi = qi0 + di, qj = qj0 + dj;
  const int a_lo = max(13 - qi, 0), b_lo = max(13 - qj, 0);
  const int ai = lane >> 1, bg = lane & 1;
  const bool active = ai < 27;
  const int a = min(a_lo + ai, 26);
  const int bs = bg ? 13 : b_lo;

  float acc[14];
#pragma unroll
  for (int j = 0; j < 14; ++j) acc[j] = 0.f;

#pragma unroll 1
  for (int cc = 0; cc < 4; ++cc) {
    __syncthreads();
    const float4* src = v1cs + ((size_t)cc * T_ + t) * HW_;
    for (int p = tid; p < RW_ * RW_; p += 256) {
      int uu = p / RW_, vv = p - uu * RW_;
      int row = min(max(qi0 - 13 + uu, 0), H_ - 1);
      int col = min(max(qj0 - 13 + vv, 0), W_ - 1);
      Rs[p] = src[row * W_ + col];
    }
    __syncthreads();
    if (active) {
#pragma unroll 1
      for (int r = 0; r < 7; ++r) {
        float4 qv[7];
        const float4* qrow = &Rs[(di + 13 + r) * RW_ + dj + 13];
#pragma unroll
        for (int s = 0; s < 7; ++s) qv[s] = qrow[s];
        const float4* crow = &Rs[(di + a + r) * RW_ + dj + bs];
#pragma unroll
        for (int y = 0; y < 20; ++y) {
          float4 vv = crow[y];
          const int s_lo = (y > 13) ? (y - 13) : 0;
          const int s_hi = (y < 6) ? y : 6;
#pragma unroll
          for (int s = s_lo; s <= s_hi; ++s) {
            float4 qq = qv[s];
            int j = y - s;
            acc[j] = fmaf(qq.x, vv.x, acc[j]);
            acc[j] = fmaf(qq.y, vv.y, acc[j]);
            acc[j] = fmaf(qq.z, vv.z, acc[j]);
            acc[j] = fmaf(qq.w, vv.w, acc[j]);
          }
        }
      }
    }
  }
  if (active) {
    const int q = ((qi >> 2) << 5) + (qj >> 2);
    float* out = distG + ((size_t)t * NQ_ + q) * NC_ + a * 27 + bs;
#pragma unroll
    for (int j = 0; j < 14; ++j) out[j] = acc[j];
  }
}

// ---------------- select: histogram top-100 + exact tie-break + softmax -----
__global__ __launch_bounds__(256) void select_kernel(
    const float* __restrict__ distG, int* __restrict__ sel_n,
    float* __restrict__ sel_w, float* __restrict__ wsum_out) {
  __shared__ float dist[NC_];
  __shared__ unsigned int ukey[NC_];
  __shared__ float red[256];
  __shared__ unsigned int hist[256];
  __shared__ int sfx[64];
  __shared__ int lk[LCAP_];
  __shared__ unsigned int lkey[LCAP_];
  __shared__ unsigned int scal[4];   // 0=beta 1=run 2=out cursor 3=list len

  const int tid = threadIdx.x;
  const int q = blockIdx.x, t = blockIdx.y;
  const int qi = (q >> 5) * S0_, qj = (q & 31) * S0_;
  const int a_lo = max(13 - qi, 0), b_lo = max(13 - qj, 0);
  const size_t base = ((size_t)t * NQ_ + q) * NC_;

  for (int h = tid; h < 256; h += 256) hist[h] = 0;
  if (tid == 0) { scal[2] = 0; scal[3] = 0; }
  for (int k = tid; k < NC_; k += 256) {
    int aa = k / 27, bb = k - aa * 27;
    int kk = max(aa, a_lo) * 27 + max(bb, b_lo);
    float d = distG[base + kk];
    dist[k] = d;
    unsigned int u = __float_as_uint(d);
    ukey[k] = u ^ (((unsigned int)((int)u >> 31)) | 0x80000000u);
  }
  __syncthreads();
  float lmax = -INFINITY;
  for (int k = tid; k < NC_; k += 256) lmax = fmaxf(lmax, dist[k]);
  red[tid] = lmax;
  __syncthreads();
  for (int off = 128; off > 0; off >>= 1) {
    if (tid < off) red[tid] = fmaxf(red[tid], red[tid + off]);
    __syncthreads();
  }
  const float dmax = red[0];
  __syncthreads();
  for (int k = tid; k < NC_; k += 256) atomicAdd(&hist[ukey[k] >> 24], 1u);
  __syncthreads();
  if (tid < 64)
    sfx[tid] = (int)(hist[tid * 4] + hist[tid * 4 + 1] + hist[tid * 4 + 2] + hist[tid * 4 + 3]);
  __syncthreads();
  for (int off = 1; off < 64; off <<= 1) {
    int v = 0;
    if (tid < 64 && tid + off < 64) v = sfx[tid + off];
    __syncthreads();
    if (tid < 64) sfx[tid] += v;
    __syncthreads();
  }
  if (tid < 64) {
    int s4 = (int)(hist[tid * 4] + hist[tid * 4 + 1] + hist[tid * 4 + 2] + hist[tid * 4 + 3]);
    int above = sfx[tid] - s4;
    if (above < KS_ && sfx[tid] >= KS_) {
      int run = above;
#pragma unroll
      for (int bb = 3; bb >= 0; --bb) {
        int h = (int)hist[tid * 4 + bb];
        if (run + h >= KS_) { scal[0] = (unsigned int)(tid * 4 + bb); scal[1] = (unsigned int)run; break; }
        run += h;
      }
    }
  }
  __syncthreads();
  const unsigned int beta = scal[0];
  const int run = (int)scal[1];
  const size_t outb = ((size_t)t * NQ_ + q) * KS_;
  float lsum = 0.f;
  for (int k = tid; k < NC_; k += 256) {
    unsigned int key = ukey[k];
    unsigned int bin = key >> 24;
    if (bin > beta) {
      unsigned int slot = atomicAdd(&scal[2], 1u);
      int aa = k / 27, bb = k - aa * 27;
      int ni = min(max(qi + aa - 13, 0), H_ - 1);
      int nj = min(max(qj + bb - 13, 0), W_ - 1);
      float wv = __expf(SCALE_ * (dist[k] - dmax));
      sel_n[outb + slot] = (ni << 7) | nj;
      sel_w[outb + slot] = wv;
      lsum += wv;
    } else if (bin == beta) {
      unsigned int pos = atomicAdd(&scal[3], 1u);
      if (pos < LCAP_) { lk[pos] = k; lkey[pos] = key; }
    }
  }
  __syncthreads();
  const int L = min((int)scal[3], LCAP_);
  for (int i = tid; i < L; i += 256) {
    unsigned int key = lkey[i];
    int k = lk[i];
    int cnt = run;
    for (int m = 0; m < L; ++m)
      cnt += (int)((lkey[m] > key) || (lkey[m] == key && lk[m] < k));
    if (cnt < KS_) {
      unsigned int slot = atomicAdd(&scal[2], 1u);
      int aa = k / 27, bb = k - aa * 27;
      int ni = min(max(qi + aa - 13, 0), H_ - 1);
      int nj = min(max(qj + bb - 13, 0), W_ - 1);
      float wv = __expf(SCALE_ * (dist[k] - dmax));
      sel_n[outb + slot] = (ni << 7) | nj;
      sel_w[outb + slot] = wv;
      lsum += wv;
    }
  }
  __syncthreads();
  red[tid] = lsum;
  __syncthreads();
  for (int off = 128; off > 0; off >>= 1) {
    if (tid < off) red[tid] += red[tid + off];
    __syncthreads();
  }
  if (tid == 0) wsum_out[t * NQ_ + q] = red[0];
}

// ---------------- weighted aggregation + fold (2x2-tile region) -------------
__global__ __launch_bounds__(256) void agg_kernel(
    const float4* __restrict__ v2cs, const int* __restrict__ sel_n,
    const float* __restrict__ sel_w, const float* __restrict__ wsum,
    float* __restrict__ Y) {
  __shared__ float4 Rs[RW_ * RW_];
  __shared__ int s_off[4][KS_];
  __shared__ float s_w[4][KS_];
  const int tid = threadIdx.x;
  const int t = blockIdx.y;
  const int qi0 = (blockIdx.x >> 4) * 8, qj0 = (blockIdx.x & 15) * 8;
  const int w = tid >> 6, lane = tid & 63;
  const int di = (w >> 1) * 4, dj = (w & 1) * 4;
  const int qi = qi0 + di, qj = qj0 + dj;
  const int q = ((qi >> 2) << 5) + (qj >> 2);
  const size_t base = ((size_t)t * NQ_ + q) * KS_;
  const float inv = 1.0f / wsum[t * NQ_ + q];
  for (int k = lane; k < KS_; k += 64) {
    int n = sel_n[base + k];
    int ni = n >> 7, nj = n & 127;
    s_off[w][k] = (ni - qi0 + 13) * RW_ + (nj - qj0 + 13);
    s_w[w][k] = sel_w[base + k] * inv;
  }
  const int r = lane / 7, s = lane - r * 7;   // valid for lane < 49
  const int myo = r * RW_ + s;
#pragma unroll 1
  for (int cc = 0; cc < 4; ++cc) {
    __syncthreads();
    const float4* src = v2cs + ((size_t)cc * T_ + t) * HW_;
    for (int p = tid; p < RW_ * RW_; p += 256) {
      int uu = p / RW_, vv = p - uu * RW_;
      int row = min(max(qi0 - 13 + uu, 0), H_ - 1);
      int col = min(max(qj0 - 13 + vv, 0), W_ - 1);
      Rs[p] = src[row * W_ + col];
    }
    __syncthreads();
    if (lane < 49) {
      float4 acc = make_float4(0.f, 0.f, 0.f, 0.f);
#pragma unroll 4
      for (int k = 0; k < KS_; ++k) {
        float wv = s_w[w][k];
        float4 v = Rs[s_off[w][k] + myo];
        acc.x = fmaf(wv, v.x, acc.x);
        acc.y = fmaf(wv, v.y, acc.y);
        acc.z = fmaf(wv, v.z, acc.z);
        acc.w = fmaf(wv, v.w, acc.w);
      }
      const int oi = min(qi + r, H_ - 1), oj = min(qj + s, W_ - 1);
      float* yb = Y + (((size_t)t * CI_ + cc * 4) * H_ + oi) * W_ + oj;
      atomicAdd(yb, acc.x);
      atomicAdd(yb + HW_, acc.y);
      atomicAdd(yb + 2 * HW_, acc.z);
      atomicAdd(yb + 3 * HW_, acc.w);
    }
  }
}

// ---------------- normalize by fold counts ----------------
__global__ void norm_kernel(float* __restrict__ Y, const float* __restrict__ Zc) {
  int idx = blockIdx.x * blockDim.x + threadIdx.x;
  if (idx >= T_ * CI_ * HW_) return;
  Y[idx] /= Zc[idx & (HW_ - 1)];
}

extern "C" void kernel_launch(void* const* d_in, const int* in_sizes, int n_in,
                              void* d_out, int out_size, void* d_ws, size_t ws_size,
                              hipStream_t stream) {
  const float* vid     = (const float*)d_in[0];
  const float* g_w     = (const float*)d_in[1];
  const float* g_b     = (const float*)d_in[2];
  const float* theta_w = (const float*)d_in[3];
  const float* theta_b = (const float*)d_in[4];
  float* Y = (float*)d_out;

  // workspace (floats): v1cs | v2cs | distG | sel_n | sel_w | wsum | Zc  (~24 MB)
  float* v1cs  = (float*)d_ws;
  float* v2cs  = v1cs + (size_t)4 * T_ * HW_ * 4;              // 1048576
  float* distG = v2cs + (size_t)4 * T_ * HW_ * 4;              // 1048576
  int*   sel_n = (int*)(distG + (size_t)T_ * NQ_ * NC_);       // 2985984
  float* sel_w = (float*)(sel_n + (size_t)T_ * NQ_ * KS_);     // 409600
  float* wsumv = sel_w + (size_t)T_ * NQ_ * KS_;               // 409600
  float* Zc    = wsumv + (size_t)T_ * NQ_;                     // 4096

  hipMemsetAsync(Y, 0, (size_t)out_size * sizeof(float), stream);
  hipMemsetAsync(Zc, 0, (size_t)HW_ * sizeof(float), stream);

  conv3x3_kernel<<<dim3(64, T_), 256, 0, stream>>>(vid, g_w, g_b, (float4*)v1cs);
  conv1x1_kernel<<<dim3(HW_ / 256, T_), 256, 0, stream>>>(vid, theta_w, theta_b, (float4*)v2cs);
  zc_kernel<<<(NQ_ * PS_ * PS_ + 255) / 256, 256, 0, stream>>>(Zc);
  dist_kernel<<<dim3(256, T_), 256, 0, stream>>>((const float4*)v1cs, distG);
  select_kernel<<<dim3(NQ_, T_), 256, 0, stream>>>(distG, sel_n, sel_w, wsumv);
  agg_kernel<<<dim3(256, T_), 256, 0, stream>>>((const float4*)v2cs, sel_n, sel_w, wsumv, Y);
  norm_kernel<<<(T_ * CI_ * HW_ + 255) / 256, 256, 0, stream>>>(Y, Zc);
}

// Round 6
// 422.294 us; speedup vs baseline: 1.2441x; 1.0227x over previous
//
#include <hip/hip_runtime.h>
#include <hip/hip_bf16.h>

#define T_ 4
#define C_ 64
#define H_ 128
#define W_ 128
#define CI_ 16
#define PS_ 7
#define NC_ 729       // 27*27 candidates per query
#define S0_ 4
#define KS_ 100
#define NQ_ 1024      // 32*32 queries per frame
#define SCALE_ 10.0f
#define HW_ (H_*W_)
#define RW_ 37        // region dim (float4); odd -> bank-quad rotation 5/row
#define LCAP_ 768

// ---------------- conv 3x3, 64->16, pad=1 (zero), chunk-major float4 output ----
// 16x16 tile/block; 16 chunks of 4 input channels; register-prefetch pipeline:
// chunk cc+1 global loads fly while chunk cc computes from LDS.
__global__ __launch_bounds__(256) void conv3x3_kernel(
    const float* __restrict__ vid, const float* __restrict__ gw,
    const float* __restrict__ gb, float4* __restrict__ v1cs) {
  __shared__ float4 tileS[18 * 19];   // stride 19 (odd) to spread banks
  const int tid = threadIdx.x;
  const int t = blockIdx.y;
  const int ti0 = (blockIdx.x >> 3) * 16, tj0 = (blockIdx.x & 7) * 16;
  const int u = tid >> 4, v = tid & 15;

  // staging slots for this thread (p = tid, tid+256)
  const int p0 = tid, p1 = tid + 256;
  const int uu0 = p0 / 18, vv0 = p0 - uu0 * 18;
  const int uu1 = p1 / 18, vv1 = p1 - uu1 * 18;
  const int gi0 = ti0 + uu0 - 1, gj0 = tj0 + vv0 - 1;
  const int gi1 = ti0 + uu1 - 1, gj1 = tj0 + vv1 - 1;
  const bool ok0 = (gi0 >= 0 && gi0 < H_ && gj0 >= 0 && gj0 < W_);
  const bool ok1 = (p1 < 324) && (gi1 >= 0 && gi1 < H_ && gj1 >= 0 && gj1 < W_);
  const int o0 = ok0 ? gi0 * W_ + gj0 : 0;
  const int o1 = ok1 ? gi1 * W_ + gj1 : 0;

  float4 pf0, pf1;
  {
    const float* vb = vid + ((size_t)(t * C_)) * HW_;
    pf0 = make_float4(0.f, 0.f, 0.f, 0.f);
    pf1 = make_float4(0.f, 0.f, 0.f, 0.f);
    if (ok0) { pf0.x = vb[o0]; pf0.y = vb[HW_ + o0]; pf0.z = vb[2 * HW_ + o0]; pf0.w = vb[3 * HW_ + o0]; }
    if (ok1) { pf1.x = vb[o1]; pf1.y = vb[HW_ + o1]; pf1.z = vb[2 * HW_ + o1]; pf1.w = vb[3 * HW_ + o1]; }
  }

  float acc[16];
#pragma unroll
  for (int co = 0; co < 16; ++co) acc[co] = gb[co];

#pragma unroll 1
  for (int cc = 0; cc < 16; ++cc) {
    __syncthreads();   // previous compute done reading LDS
    tileS[uu0 * 19 + vv0] = pf0;
    if (p1 < 324) tileS[uu1 * 19 + vv1] = pf1;
    __syncthreads();
    if (cc < 15) {     // prefetch next chunk while computing this one
      const float* vb = vid + ((size_t)(t * C_ + (cc + 1) * 4)) * HW_;
      pf0 = make_float4(0.f, 0.f, 0.f, 0.f);
      pf1 = make_float4(0.f, 0.f, 0.f, 0.f);
      if (ok0) { pf0.x = vb[o0]; pf0.y = vb[HW_ + o0]; pf0.z = vb[2 * HW_ + o0]; pf0.w = vb[3 * HW_ + o0]; }
      if (ok1) { pf1.x = vb[o1]; pf1.y = vb[HW_ + o1]; pf1.z = vb[2 * HW_ + o1]; pf1.w = vb[3 * HW_ + o1]; }
    }
    float4 n[9];
#pragma unroll
    for (int ki = 0; ki < 3; ++ki)
#pragma unroll
      for (int kj = 0; kj < 3; ++kj)
        n[ki * 3 + kj] = tileS[(u + ki) * 19 + v + kj];
#pragma unroll
    for (int co = 0; co < 16; ++co) {
      const float* wc = gw + ((size_t)co * C_ + cc * 4) * 9;
#pragma unroll
      for (int k = 0; k < 9; ++k) {
        acc[co] = fmaf(wc[k],      n[k].x, acc[co]);
        acc[co] = fmaf(wc[9 + k],  n[k].y, acc[co]);
        acc[co] = fmaf(wc[18 + k], n[k].z, acc[co]);
        acc[co] = fmaf(wc[27 + k], n[k].w, acc[co]);
      }
    }
  }
  const int pix = (ti0 + u) * W_ + tj0 + v;
#pragma unroll
  for (int g = 0; g < 4; ++g)
    v1cs[((size_t)g * T_ + t) * HW_ + pix] =
        make_float4(acc[4 * g], acc[4 * g + 1], acc[4 * g + 2], acc[4 * g + 3]);
}

// ---------------- conv 1x1, 64->16, chunk-major float4 output ----------------
// 8-wide load batches: 8 independent global loads in flight per group.
__global__ __launch_bounds__(256) void conv1x1_kernel(
    const float* __restrict__ vid, const float* __restrict__ tw,
    const float* __restrict__ tb, float4* __restrict__ v2cs) {
  __shared__ float w[C_ * CI_];   // w[c*16 + o]
  const int t = blockIdx.y;
  for (int m = threadIdx.x; m < C_ * CI_; m += 256) {
    int o = m & 15, c = m >> 4;
    w[m] = tw[o * C_ + c];
  }
  __syncthreads();
  const int pix = blockIdx.x * 256 + threadIdx.x;
  float acc[CI_];
#pragma unroll
  for (int o = 0; o < CI_; ++o) acc[o] = tb[o];
  const float* vb = vid + ((size_t)t * C_) * HW_ + pix;
#pragma unroll 1
  for (int c0 = 0; c0 < C_; c0 += 8) {
    float x[8];
#pragma unroll
    for (int uu = 0; uu < 8; ++uu) x[uu] = vb[(size_t)(c0 + uu) * HW_];
#pragma unroll
    for (int uu = 0; uu < 8; ++uu)
#pragma unroll
      for (int o = 0; o < 16; ++o)
        acc[o] = fmaf(w[(c0 + uu) * 16 + o], x[uu], acc[o]);
  }
#pragma unroll
  for (int cc = 0; cc < 4; ++cc)
    v2cs[((size_t)cc * T_ + t) * HW_ + pix] =
        make_float4(acc[cc * 4], acc[cc * 4 + 1], acc[cc * 4 + 2], acc[cc * 4 + 3]);
}

// ---------------- Zc: fold counts ----------------
__global__ void zc_kernel(float* __restrict__ Zc) {
  int idx = blockIdx.x * blockDim.x + threadIdx.x;
  if (idx >= NQ_ * PS_ * PS_) return;
  int q = idx / 49, rs = idx - q * 49;
  int qi = (q >> 5) * S0_, qj = (q & 31) * S0_;
  int r = rs / 7, s = rs - r * 7;
  atomicAdd(&Zc[min(qi + r, H_ - 1) * W_ + min(qj + s, W_ - 1)], 1.0f);
}

// ---------------- dists: 2x2-query-tile region, wave=query, j=14/lane ------
__global__ __launch_bounds__(256) void dist_kernel(
    const float4* __restrict__ v1cs, float* __restrict__ distG) {
  __shared__ float4 Rs[RW_ * RW_];
  const int tid = threadIdx.x;
  const int t = blockIdx.y;
  const int qi0 = (blockIdx.x >> 4) * 8, qj0 = (blockIdx.x & 15) * 8;
  const int w = tid >> 6, lane = tid & 63;
  const int di = (w >> 1) * 4, dj = (w & 1) * 4;
  const int qi = qi0 + di, qj = qj0 + dj;
  const int a_lo = max(13 - qi, 0), b_lo = max(13 - qj, 0);
  const int ai = lane >> 1, bg = lane & 1;
  const bool active = ai < 27;
  const int a = min(a_lo + ai, 26);
  const int bs = bg ? 13 : b_lo;

  float acc[14];
#pragma unroll
  for (int j = 0; j < 14; ++j) acc[j] = 0.f;

#pragma unroll 1
  for (int cc = 0; cc < 4; ++cc) {
    __syncthreads();
    const float4* src = v1cs + ((size_t)cc * T_ + t) * HW_;
    for (int p = tid; p < RW_ * RW_; p += 256) {
      int uu = p / RW_, vv = p - uu * RW_;
      int row = min(max(qi0 - 13 + uu, 0), H_ - 1);
      int col = min(max(qj0 - 13 + vv, 0), W_ - 1);
      Rs[p] = src[row * W_ + col];
    }
    __syncthreads();
    if (active) {
#pragma unroll 1
      for (int r = 0; r < 7; ++r) {
        float4 qv[7];
        const float4* qrow = &Rs[(di + 13 + r) * RW_ + dj + 13];
#pragma unroll
        for (int s = 0; s < 7; ++s) qv[s] = qrow[s];
        const float4* crow = &Rs[(di + a + r) * RW_ + dj + bs];
#pragma unroll
        for (int y = 0; y < 20; ++y) {
          float4 vv = crow[y];
          const int s_lo = (y > 13) ? (y - 13) : 0;
          const int s_hi = (y < 6) ? y : 6;
#pragma unroll
          for (int s = s_lo; s <= s_hi; ++s) {
            float4 qq = qv[s];
            int j = y - s;
            acc[j] = fmaf(qq.x, vv.x, acc[j]);
            acc[j] = fmaf(qq.y, vv.y, acc[j]);
            acc[j] = fmaf(qq.z, vv.z, acc[j]);
            acc[j] = fmaf(qq.w, vv.w, acc[j]);
          }
        }
      }
    }
  }
  if (active) {
    const int q = ((qi >> 2) << 5) + (qj >> 2);
    float* out = distG + ((size_t)t * NQ_ + q) * NC_ + a * 27 + bs;
#pragma unroll
    for (int j = 0; j < 14; ++j) out[j] = acc[j];
  }
}

// ---------------- select: histogram top-100 + exact tie-break + softmax -----
__global__ __launch_bounds__(256) void select_kernel(
    const float* __restrict__ distG, int* __restrict__ sel_n,
    float* __restrict__ sel_w, float* __restrict__ wsum_out) {
  __shared__ float dist[NC_];
  __shared__ unsigned int ukey[NC_];
  __shared__ float red[256];
  __shared__ unsigned int hist[256];
  __shared__ int sfx[64];
  __shared__ int lk[LCAP_];
  __shared__ unsigned int lkey[LCAP_];
  __shared__ unsigned int scal[4];   // 0=beta 1=run 2=out cursor 3=list len

  const int tid = threadIdx.x;
  const int q = blockIdx.x, t = blockIdx.y;
  const int qi = (q >> 5) * S0_, qj = (q & 31) * S0_;
  const int a_lo = max(13 - qi, 0), b_lo = max(13 - qj, 0);
  const size_t base = ((size_t)t * NQ_ + q) * NC_;

  for (int h = tid; h < 256; h += 256) hist[h] = 0;
  if (tid == 0) { scal[2] = 0; scal[3] = 0; }
  for (int k = tid; k < NC_; k += 256) {
    int aa = k / 27, bb = k - aa * 27;
    int kk = max(aa, a_lo) * 27 + max(bb, b_lo);
    float d = distG[base + kk];
    dist[k] = d;
    unsigned int u = __float_as_uint(d);
    ukey[k] = u ^ (((unsigned int)((int)u >> 31)) | 0x80000000u);
  }
  __syncthreads();
  float lmax = -INFINITY;
  for (int k = tid; k < NC_; k += 256) lmax = fmaxf(lmax, dist[k]);
  red[tid] = lmax;
  __syncthreads();
  for (int off = 128; off > 0; off >>= 1) {
    if (tid < off) red[tid] = fmaxf(red[tid], red[tid + off]);
    __syncthreads();
  }
  const float dmax = red[0];
  __syncthreads();
  for (int k = tid; k < NC_; k += 256) atomicAdd(&hist[ukey[k] >> 24], 1u);
  __syncthreads();
  if (tid < 64)
    sfx[tid] = (int)(hist[tid * 4] + hist[tid * 4 + 1] + hist[tid * 4 + 2] + hist[tid * 4 + 3]);
  __syncthreads();
  for (int off = 1; off < 64; off <<= 1) {
    int v = 0;
    if (tid < 64 && tid + off < 64) v = sfx[tid + off];
    __syncthreads();
    if (tid < 64) sfx[tid] += v;
    __syncthreads();
  }
  if (tid < 64) {
    int s4 = (int)(hist[tid * 4] + hist[tid * 4 + 1] + hist[tid * 4 + 2] + hist[tid * 4 + 3]);
    int above = sfx[tid] - s4;
    if (above < KS_ && sfx[tid] >= KS_) {
      int run = above;
#pragma unroll
      for (int bb = 3; bb >= 0; --bb) {
        int h = (int)hist[tid * 4 + bb];
        if (run + h >= KS_) { scal[0] = (unsigned int)(tid * 4 + bb); scal[1] = (unsigned int)run; break; }
        run += h;
      }
    }
  }
  __syncthreads();
  const unsigned int beta = scal[0];
  const int run = (int)scal[1];
  const size_t outb = ((size_t)t * NQ_ + q) * KS_;
  float lsum = 0.f;
  for (int k = tid; k < NC_; k += 256) {
    unsigned int key = ukey[k];
    unsigned int bin = key >> 24;
    if (bin > beta) {
      unsigned int slot = atomicAdd(&scal[2], 1u);
      int aa = k / 27, bb = k - aa * 27;
      int ni = min(max(qi + aa - 13, 0), H_ - 1);
      int nj = min(max(qj + bb - 13, 0), W_ - 1);
      float wv = __expf(SCALE_ * (dist[k] - dmax));
      sel_n[outb + slot] = (ni << 7) | nj;
      sel_w[outb + slot] = wv;
      lsum += wv;
    } else if (bin == beta) {
      unsigned int pos = atomicAdd(&scal[3], 1u);
      if (pos < LCAP_) { lk[pos] = k; lkey[pos] = key; }
    }
  }
  __syncthreads();
  const int L = min((int)scal[3], LCAP_);
  for (int i = tid; i < L; i += 256) {
    unsigned int key = lkey[i];
    int k = lk[i];
    int cnt = run;
    for (int m = 0; m < L; ++m)
      cnt += (int)((lkey[m] > key) || (lkey[m] == key && lk[m] < k));
    if (cnt < KS_) {
      unsigned int slot = atomicAdd(&scal[2], 1u);
      int aa = k / 27, bb = k - aa * 27;
      int ni = min(max(qi + aa - 13, 0), H_ - 1);
      int nj = min(max(qj + bb - 13, 0), W_ - 1);
      float wv = __expf(SCALE_ * (dist[k] - dmax));
      sel_n[outb + slot] = (ni << 7) | nj;
      sel_w[outb + slot] = wv;
      lsum += wv;
    }
  }
  __syncthreads();
  red[tid] = lsum;
  __syncthreads();
  for (int off = 128; off > 0; off >>= 1) {
    if (tid < off) red[tid] += red[tid + off];
    __syncthreads();
  }
  if (tid == 0) wsum_out[t * NQ_ + q] = red[0];
}

// ---------------- weighted aggregation + fold (2x2-tile region) -------------
__global__ __launch_bounds__(256) void agg_kernel(
    const float4* __restrict__ v2cs, const int* __restrict__ sel_n,
    const float* __restrict__ sel_w, const float* __restrict__ wsum,
    float* __restrict__ Y) {
  __shared__ float4 Rs[RW_ * RW_];
  __shared__ int s_off[4][KS_];
  __shared__ float s_w[4][KS_];
  const int tid = threadIdx.x;
  const int t = blockIdx.y;
  const int qi0 = (blockIdx.x >> 4) * 8, qj0 = (blockIdx.x & 15) * 8;
  const int w = tid >> 6, lane = tid & 63;
  const int di = (w >> 1) * 4, dj = (w & 1) * 4;
  const int qi = qi0 + di, qj = qj0 + dj;
  const int q = ((qi >> 2) << 5) + (qj >> 2);
  const size_t base = ((size_t)t * NQ_ + q) * KS_;
  const float inv = 1.0f / wsum[t * NQ_ + q];
  for (int k = lane; k < KS_; k += 64) {
    int n = sel_n[base + k];
    int ni = n >> 7, nj = n & 127;
    s_off[w][k] = (ni - qi0 + 13) * RW_ + (nj - qj0 + 13);
    s_w[w][k] = sel_w[base + k] * inv;
  }
  const int r = lane / 7, s = lane - r * 7;   // valid for lane < 49
  const int myo = r * RW_ + s;
#pragma unroll 1
  for (int cc = 0; cc < 4; ++cc) {
    __syncthreads();
    const float4* src = v2cs + ((size_t)cc * T_ + t) * HW_;
    for (int p = tid; p < RW_ * RW_; p += 256) {
      int uu = p / RW_, vv = p - uu * RW_;
      int row = min(max(qi0 - 13 + uu, 0), H_ - 1);
      int col = min(max(qj0 - 13 + vv, 0), W_ - 1);
      Rs[p] = src[row * W_ + col];
    }
    __syncthreads();
    if (lane < 49) {
      float4 acc = make_float4(0.f, 0.f, 0.f, 0.f);
#pragma unroll 4
      for (int k = 0; k < KS_; ++k) {
        float wv = s_w[w][k];
        float4 v = Rs[s_off[w][k] + myo];
        acc.x = fmaf(wv, v.x, acc.x);
        acc.y = fmaf(wv, v.y, acc.y);
        acc.z = fmaf(wv, v.z, acc.z);
        acc.w = fmaf(wv, v.w, acc.w);
      }
      const int oi = min(qi + r, H_ - 1), oj = min(qj + s, W_ - 1);
      float* yb = Y + (((size_t)t * CI_ + cc * 4) * H_ + oi) * W_ + oj;
      atomicAdd(yb, acc.x);
      atomicAdd(yb + HW_, acc.y);
      atomicAdd(yb + 2 * HW_, acc.z);
      atomicAdd(yb + 3 * HW_, acc.w);
    }
  }
}

// ---------------- normalize by fold counts ----------------
__global__ void norm_kernel(float* __restrict__ Y, const float* __restrict__ Zc) {
  int idx = blockIdx.x * blockDim.x + threadIdx.x;
  if (idx >= T_ * CI_ * HW_) return;
  Y[idx] /= Zc[idx & (HW_ - 1)];
}

extern "C" void kernel_launch(void* const* d_in, const int* in_sizes, int n_in,
                              void* d_out, int out_size, void* d_ws, size_t ws_size,
                              hipStream_t stream) {
  const float* vid     = (const float*)d_in[0];
  const float* g_w     = (const float*)d_in[1];
  const float* g_b     = (const float*)d_in[2];
  const float* theta_w = (const float*)d_in[3];
  const float* theta_b = (const float*)d_in[4];
  float* Y = (float*)d_out;

  // workspace (floats): v1cs | v2cs | distG | sel_n | sel_w | wsum | Zc  (~24 MB)
  float* v1cs  = (float*)d_ws;
  float* v2cs  = v1cs + (size_t)4 * T_ * HW_ * 4;              // 1048576
  float* distG = v2cs + (size_t)4 * T_ * HW_ * 4;              // 1048576
  int*   sel_n = (int*)(distG + (size_t)T_ * NQ_ * NC_);       // 2985984
  float* sel_w = (float*)(sel_n + (size_t)T_ * NQ_ * KS_);     // 409600
  float* wsumv = sel_w + (size_t)T_ * NQ_ * KS_;               // 409600
  float* Zc    = wsumv + (size_t)T_ * NQ_;                     // 4096

  hipMemsetAsync(Y, 0, (size_t)out_size * sizeof(float), stream);
  hipMemsetAsync(Zc, 0, (size_t)HW_ * sizeof(float), stream);

  conv3x3_kernel<<<dim3(64, T_), 256, 0, stream>>>(vid, g_w, g_b, (float4*)v1cs);
  conv1x1_kernel<<<dim3(HW_ / 256, T_), 256, 0, stream>>>(vid, theta_w, theta_b, (float4*)v2cs);
  zc_kernel<<<(NQ_ * PS_ * PS_ + 255) / 256, 256, 0, stream>>>(Zc);
  dist_kernel<<<dim3(256, T_), 256, 0, stream>>>((const float4*)v1cs, distG);
  select_kernel<<<dim3(NQ_, T_), 256, 0, stream>>>(distG, sel_n, sel_w, wsumv);
  agg_kernel<<<dim3(256, T_), 256, 0, stream>>>((const float4*)v2cs, sel_n, sel_w, wsumv, Y);
  norm_kernel<<<(T_ * CI_ * HW_ + 255) / 256, 256, 0, stream>>>(Y, Zc);
}

// Round 7
// 395.336 us; speedup vs baseline: 1.3290x; 1.0682x over previous
//
#include <hip/hip_runtime.h>
#include <hip/hip_bf16.h>

#define T_ 4
#define C_ 64
#define H_ 128
#define W_ 128
#define CI_ 16
#define PS_ 7
#define NC_ 729       // 27*27 candidates per query
#define S0_ 4
#define KS_ 100
#define NQ_ 1024      // 32*32 queries per frame
#define SCALE_ 10.0f
#define HW_ (H_*W_)
#define RW_ 37        // region dim (float4); odd -> bank-quad rotation 5/row
#define LCAP_ 768

// ---------------- conv 3x3, 64->16, pad=1 (zero), chunk-major float4 output ----
// co split across 2 blocks (8 each) -> 512 blocks = 2/CU = 8 waves/CU.
// 16x16 tile; 16 chunks of 4 input channels; register-prefetch pipeline.
__global__ __launch_bounds__(256) void conv3x3_kernel(
    const float* __restrict__ vid, const float* __restrict__ gw,
    const float* __restrict__ gb, float4* __restrict__ v1cs) {
  __shared__ float4 tileS[18 * 19];   // stride 19 (odd) to spread banks
  const int tid = threadIdx.x;
  const int g = blockIdx.y;           // co-group: co = g*8 .. g*8+7
  const int t = blockIdx.z;
  const int ti0 = (blockIdx.x >> 3) * 16, tj0 = (blockIdx.x & 7) * 16;
  const int u = tid >> 4, v = tid & 15;

  const int p0 = tid, p1 = tid + 256;
  const int uu0 = p0 / 18, vv0 = p0 - uu0 * 18;
  const int uu1 = p1 / 18, vv1 = p1 - uu1 * 18;
  const int gi0 = ti0 + uu0 - 1, gj0 = tj0 + vv0 - 1;
  const int gi1 = ti0 + uu1 - 1, gj1 = tj0 + vv1 - 1;
  const bool ok0 = (gi0 >= 0 && gi0 < H_ && gj0 >= 0 && gj0 < W_);
  const bool ok1 = (p1 < 324) && (gi1 >= 0 && gi1 < H_ && gj1 >= 0 && gj1 < W_);
  const int o0 = ok0 ? gi0 * W_ + gj0 : 0;
  const int o1 = ok1 ? gi1 * W_ + gj1 : 0;

  float4 pf0, pf1;
  {
    const float* vb = vid + ((size_t)(t * C_)) * HW_;
    pf0 = make_float4(0.f, 0.f, 0.f, 0.f);
    pf1 = make_float4(0.f, 0.f, 0.f, 0.f);
    if (ok0) { pf0.x = vb[o0]; pf0.y = vb[HW_ + o0]; pf0.z = vb[2 * HW_ + o0]; pf0.w = vb[3 * HW_ + o0]; }
    if (ok1) { pf1.x = vb[o1]; pf1.y = vb[HW_ + o1]; pf1.z = vb[2 * HW_ + o1]; pf1.w = vb[3 * HW_ + o1]; }
  }

  float acc[8];
#pragma unroll
  for (int co = 0; co < 8; ++co) acc[co] = gb[g * 8 + co];

#pragma unroll 1
  for (int cc = 0; cc < 16; ++cc) {
    __syncthreads();
    tileS[uu0 * 19 + vv0] = pf0;
    if (p1 < 324) tileS[uu1 * 19 + vv1] = pf1;
    __syncthreads();
    if (cc < 15) {
      const float* vb = vid + ((size_t)(t * C_ + (cc + 1) * 4)) * HW_;
      pf0 = make_float4(0.f, 0.f, 0.f, 0.f);
      pf1 = make_float4(0.f, 0.f, 0.f, 0.f);
      if (ok0) { pf0.x = vb[o0]; pf0.y = vb[HW_ + o0]; pf0.z = vb[2 * HW_ + o0]; pf0.w = vb[3 * HW_ + o0]; }
      if (ok1) { pf1.x = vb[o1]; pf1.y = vb[HW_ + o1]; pf1.z = vb[2 * HW_ + o1]; pf1.w = vb[3 * HW_ + o1]; }
    }
    float4 n[9];
#pragma unroll
    for (int ki = 0; ki < 3; ++ki)
#pragma unroll
      for (int kj = 0; kj < 3; ++kj)
        n[ki * 3 + kj] = tileS[(u + ki) * 19 + v + kj];
#pragma unroll
    for (int co = 0; co < 8; ++co) {
      const float* wc = gw + ((size_t)(g * 8 + co) * C_ + cc * 4) * 9;
#pragma unroll
      for (int k = 0; k < 9; ++k) {
        acc[co] = fmaf(wc[k],      n[k].x, acc[co]);
        acc[co] = fmaf(wc[9 + k],  n[k].y, acc[co]);
        acc[co] = fmaf(wc[18 + k], n[k].z, acc[co]);
        acc[co] = fmaf(wc[27 + k], n[k].w, acc[co]);
      }
    }
  }
  const int pix = (ti0 + u) * W_ + tj0 + v;
  v1cs[((size_t)(g * 2) * T_ + t) * HW_ + pix]     = make_float4(acc[0], acc[1], acc[2], acc[3]);
  v1cs[((size_t)(g * 2 + 1) * T_ + t) * HW_ + pix] = make_float4(acc[4], acc[5], acc[6], acc[7]);
}

// ---------------- conv 1x1, 64->16, chunk-major float4 output ----------------
__global__ __launch_bounds__(256) void conv1x1_kernel(
    const float* __restrict__ vid, const float* __restrict__ tw,
    const float* __restrict__ tb, float4* __restrict__ v2cs) {
  __shared__ float w[C_ * CI_];   // w[c*16 + o]
  const int t = blockIdx.y;
  for (int m = threadIdx.x; m < C_ * CI_; m += 256) {
    int o = m & 15, c = m >> 4;
    w[m] = tw[o * C_ + c];
  }
  __syncthreads();
  const int pix = blockIdx.x * 256 + threadIdx.x;
  float acc[CI_];
#pragma unroll
  for (int o = 0; o < CI_; ++o) acc[o] = tb[o];
  const float* vb = vid + ((size_t)t * C_) * HW_ + pix;
#pragma unroll 1
  for (int c0 = 0; c0 < C_; c0 += 8) {
    float x[8];
#pragma unroll
    for (int uu = 0; uu < 8; ++uu) x[uu] = vb[(size_t)(c0 + uu) * HW_];
#pragma unroll
    for (int uu = 0; uu < 8; ++uu)
#pragma unroll
      for (int o = 0; o < 16; ++o)
        acc[o] = fmaf(w[(c0 + uu) * 16 + o], x[uu], acc[o]);
  }
#pragma unroll
  for (int cc = 0; cc < 4; ++cc)
    v2cs[((size_t)cc * T_ + t) * HW_ + pix] =
        make_float4(acc[cc * 4], acc[cc * 4 + 1], acc[cc * 4 + 2], acc[cc * 4 + 3]);
}

// ---------------- dists: 2x2-query-tile region, wave=query, j=14/lane ------
__global__ __launch_bounds__(256) void dist_kernel(
    const float4* __restrict__ v1cs, float* __restrict__ distG) {
  __shared__ float4 Rs[RW_ * RW_];
  const int tid = threadIdx.x;
  const int t = blockIdx.y;
  const int qi0 = (blockIdx.x >> 4) * 8, qj0 = (blockIdx.x & 15) * 8;
  const int w = tid >> 6, lane = tid & 63;
  const int di = (w >> 1) * 4, dj = (w & 1) * 4;
  const int qi = qi0 + di, qj = qj0 + dj;
  const int a_lo = max(13 - qi, 0), b_lo = max(13 - qj, 0);
  const int ai = lane >> 1, bg = lane & 1;
  const bool active = ai < 27;
  const int a = min(a_lo + ai, 26);
  const int bs = bg ? 13 : b_lo;

  float acc[14];
#pragma unroll
  for (int j = 0; j < 14; ++j) acc[j] = 0.f;

#pragma unroll 1
  for (int cc = 0; cc < 4; ++cc) {
    __syncthreads();
    const float4* src = v1cs + ((size_t)cc * T_ + t) * HW_;
    for (int p = tid; p < RW_ * RW_; p += 256) {
      int uu = p / RW_, vv = p - uu * RW_;
      int row = min(max(qi0 - 13 + uu, 0), H_ - 1);
      int col = min(max(qj0 - 13 + vv, 0), W_ - 1);
      Rs[p] = src[row * W_ + col];
    }
    __syncthreads();
    if (active) {
#pragma unroll 1
      for (int r = 0; r < 7; ++r) {
        float4 qv[7];
        const float4* qrow = &Rs[(di + 13 + r) * RW_ + dj + 13];
#pragma unroll
        for (int s = 0; s < 7; ++s) qv[s] = qrow[s];
        const float4* crow = &Rs[(di + a + r) * RW_ + dj + bs];
#pragma unroll
        for (int y = 0; y < 20; ++y) {
          float4 vv = crow[y];
          const int s_lo = (y > 13) ? (y - 13) : 0;
          const int s_hi = (y < 6) ? y : 6;
#pragma unroll
          for (int s = s_lo; s <= s_hi; ++s) {
            float4 qq = qv[s];
            int j = y - s;
            acc[j] = fmaf(qq.x, vv.x, acc[j]);
            acc[j] = fmaf(qq.y, vv.y, acc[j]);
            acc[j] = fmaf(qq.z, vv.z, acc[j]);
            acc[j] = fmaf(qq.w, vv.w, acc[j]);
          }
        }
      }
    }
  }
  if (active) {
    const int q = ((qi >> 2) << 5) + (qj >> 2);
    float* out = distG + ((size_t)t * NQ_ + q) * NC_ + a * 27 + bs;
#pragma unroll
    for (int j = 0; j < 14; ++j) out[j] = acc[j];
  }
}

// ---------------- select: histogram top-100 + exact tie-break + softmax -----
__global__ __launch_bounds__(256) void select_kernel(
    const float* __restrict__ distG, int* __restrict__ sel_n,
    float* __restrict__ sel_w, float* __restrict__ wsum_out) {
  __shared__ float dist[NC_];
  __shared__ unsigned int ukey[NC_];
  __shared__ float red[256];
  __shared__ unsigned int hist[256];
  __shared__ int sfx[64];
  __shared__ int lk[LCAP_];
  __shared__ unsigned int lkey[LCAP_];
  __shared__ unsigned int scal[4];   // 0=beta 1=run 2=out cursor 3=list len

  const int tid = threadIdx.x;
  const int q = blockIdx.x, t = blockIdx.y;
  const int qi = (q >> 5) * S0_, qj = (q & 31) * S0_;
  const int a_lo = max(13 - qi, 0), b_lo = max(13 - qj, 0);
  const size_t base = ((size_t)t * NQ_ + q) * NC_;

  for (int h = tid; h < 256; h += 256) hist[h] = 0;
  if (tid == 0) { scal[2] = 0; scal[3] = 0; }
  for (int k = tid; k < NC_; k += 256) {
    int aa = k / 27, bb = k - aa * 27;
    int kk = max(aa, a_lo) * 27 + max(bb, b_lo);
    float d = distG[base + kk];
    dist[k] = d;
    unsigned int u = __float_as_uint(d);
    ukey[k] = u ^ (((unsigned int)((int)u >> 31)) | 0x80000000u);
  }
  __syncthreads();
  float lmax = -INFINITY;
  for (int k = tid; k < NC_; k += 256) lmax = fmaxf(lmax, dist[k]);
  red[tid] = lmax;
  __syncthreads();
  for (int off = 128; off > 0; off >>= 1) {
    if (tid < off) red[tid] = fmaxf(red[tid], red[tid + off]);
    __syncthreads();
  }
  const float dmax = red[0];
  __syncthreads();
  for (int k = tid; k < NC_; k += 256) atomicAdd(&hist[ukey[k] >> 24], 1u);
  __syncthreads();
  if (tid < 64)
    sfx[tid] = (int)(hist[tid * 4] + hist[tid * 4 + 1] + hist[tid * 4 + 2] + hist[tid * 4 + 3]);
  __syncthreads();
  for (int off = 1; off < 64; off <<= 1) {
    int v = 0;
    if (tid < 64 && tid + off < 64) v = sfx[tid + off];
    __syncthreads();
    if (tid < 64) sfx[tid] += v;
    __syncthreads();
  }
  if (tid < 64) {
    int s4 = (int)(hist[tid * 4] + hist[tid * 4 + 1] + hist[tid * 4 + 2] + hist[tid * 4 + 3]);
    int above = sfx[tid] - s4;
    if (above < KS_ && sfx[tid] >= KS_) {
      int run = above;
#pragma unroll
      for (int bb = 3; bb >= 0; --bb) {
        int h = (int)hist[tid * 4 + bb];
        if (run + h >= KS_) { scal[0] = (unsigned int)(tid * 4 + bb); scal[1] = (unsigned int)run; break; }
        run += h;
      }
    }
  }
  __syncthreads();
  const unsigned int beta = scal[0];
  const int run = (int)scal[1];
  const size_t outb = ((size_t)t * NQ_ + q) * KS_;
  float lsum = 0.f;
  for (int k = tid; k < NC_; k += 256) {
    unsigned int key = ukey[k];
    unsigned int bin = key >> 24;
    if (bin > beta) {
      unsigned int slot = atomicAdd(&scal[2], 1u);
      int aa = k / 27, bb = k - aa * 27;
      int ni = min(max(qi + aa - 13, 0), H_ - 1);
      int nj = min(max(qj + bb - 13, 0), W_ - 1);
      float wv = __expf(SCALE_ * (dist[k] - dmax));
      sel_n[outb + slot] = (ni << 7) | nj;
      sel_w[outb + slot] = wv;
      lsum += wv;
    } else if (bin == beta) {
      unsigned int pos = atomicAdd(&scal[3], 1u);
      if (pos < LCAP_) { lk[pos] = k; lkey[pos] = key; }
    }
  }
  __syncthreads();
  const int L = min((int)scal[3], LCAP_);
  for (int i = tid; i < L; i += 256) {
    unsigned int key = lkey[i];
    int k = lk[i];
    int cnt = run;
    for (int m = 0; m < L; ++m)
      cnt += (int)((lkey[m] > key) || (lkey[m] == key && lk[m] < k));
    if (cnt < KS_) {
      unsigned int slot = atomicAdd(&scal[2], 1u);
      int aa = k / 27, bb = k - aa * 27;
      int ni = min(max(qi + aa - 13, 0), H_ - 1);
      int nj = min(max(qj + bb - 13, 0), W_ - 1);
      float wv = __expf(SCALE_ * (dist[k] - dmax));
      sel_n[outb + slot] = (ni << 7) | nj;
      sel_w[outb + slot] = wv;
      lsum += wv;
    }
  }
  __syncthreads();
  red[tid] = lsum;
  __syncthreads();
  for (int off = 128; off > 0; off >>= 1) {
    if (tid < off) red[tid] += red[tid + off];
    __syncthreads();
  }
  if (tid == 0) wsum_out[t * NQ_ + q] = red[0];
}

// ---------------- weighted aggregation + fold (direct L2 gather) ------------
// 4096 blocks = 16/CU; 256 threads = 4 cc-groups of 64; lane<49 = (r,s).
// No LDS region -> no bank conflicts, no staging barriers; L2 supplies reuse.
__global__ __launch_bounds__(256) void agg_kernel(
    const float4* __restrict__ v2cs, const int* __restrict__ sel_n,
    const float* __restrict__ sel_w, const float* __restrict__ wsum,
    float* __restrict__ Y) {
  __shared__ int s_ni[KS_], s_nj[KS_];
  __shared__ float s_w[KS_];
  const int tid = threadIdx.x;
  const int q = blockIdx.x, t = blockIdx.y;
  const int qi = (q >> 5) * S0_, qj = (q & 31) * S0_;
  const size_t base = ((size_t)t * NQ_ + q) * KS_;
  if (tid < KS_) {
    int n = sel_n[base + tid];
    s_ni[tid] = n >> 7;
    s_nj[tid] = n & 127;
    s_w[tid] = sel_w[base + tid] / wsum[t * NQ_ + q];
  }
  __syncthreads();
  const int cc = tid >> 6, lane = tid & 63;
  if (lane >= 49) return;
  const int r = lane / 7, s = lane - r * 7;
  const float4* src = v2cs + ((size_t)cc * T_ + t) * HW_;
  float4 acc = make_float4(0.f, 0.f, 0.f, 0.f);
#pragma unroll 4
  for (int k = 0; k < KS_; ++k) {
    int ri = min(s_ni[k] + r, H_ - 1);
    int ci = min(s_nj[k] + s, W_ - 1);
    float4 v = src[ri * W_ + ci];
    float w = s_w[k];
    acc.x = fmaf(w, v.x, acc.x);
    acc.y = fmaf(w, v.y, acc.y);
    acc.z = fmaf(w, v.z, acc.z);
    acc.w = fmaf(w, v.w, acc.w);
  }
  const int oi = min(qi + r, H_ - 1), oj = min(qj + s, W_ - 1);
  float* yb = Y + (((size_t)t * CI_ + cc * 4) * H_ + oi) * W_ + oj;
  atomicAdd(yb, acc.x);
  atomicAdd(yb + HW_, acc.y);
  atomicAdd(yb + 2 * HW_, acc.z);
  atomicAdd(yb + 3 * HW_, acc.w);
}

// ---------------- normalize by analytic fold counts -------------------------
// Zc(i,j) = cov(i)*cov(j): coverage count of the clamped 7-patch fold on a
// stride-4 query grid (qb in {0,4,...,124}).
__device__ __forceinline__ int cov_axis(int x) {
  int c = 0;
#pragma unroll
  for (int r = 0; r < 7; ++r) {
    if (x < H_ - 1) {
      int qb = x - r;
      c += (qb >= 0 && (qb & 3) == 0) ? 1 : 0;
    } else {
      // x == 127: count qb multiples of 4 in [127-r, 124]
      c += (r >= 3) ? 1 : 0;
    }
  }
  return c;
}

__global__ void norm_kernel(float* __restrict__ Y) {
  int idx = blockIdx.x * blockDim.x + threadIdx.x;
  if (idx >= T_ * CI_ * HW_) return;
  int p = idx & (HW_ - 1);
  float z = (float)(cov_axis(p >> 7) * cov_axis(p & 127));
  Y[idx] /= z;
}

extern "C" void kernel_launch(void* const* d_in, const int* in_sizes, int n_in,
                              void* d_out, int out_size, void* d_ws, size_t ws_size,
                              hipStream_t stream) {
  const float* vid     = (const float*)d_in[0];
  const float* g_w     = (const float*)d_in[1];
  const float* g_b     = (const float*)d_in[2];
  const float* theta_w = (const float*)d_in[3];
  const float* theta_b = (const float*)d_in[4];
  float* Y = (float*)d_out;

  // workspace (floats): v1cs | v2cs | distG | sel_n | sel_w | wsum  (~24 MB)
  float* v1cs  = (float*)d_ws;
  float* v2cs  = v1cs + (size_t)4 * T_ * HW_ * 4;              // 1048576
  float* distG = v2cs + (size_t)4 * T_ * HW_ * 4;              // 1048576
  int*   sel_n = (int*)(distG + (size_t)T_ * NQ_ * NC_);       // 2985984
  float* sel_w = (float*)(sel_n + (size_t)T_ * NQ_ * KS_);     // 409600
  float* wsumv = sel_w + (size_t)T_ * NQ_ * KS_;               // 409600

  hipMemsetAsync(Y, 0, (size_t)out_size * sizeof(float), stream);

  conv3x3_kernel<<<dim3(64, 2, T_), 256, 0, stream>>>(vid, g_w, g_b, (float4*)v1cs);
  conv1x1_kernel<<<dim3(HW_ / 256, T_), 256, 0, stream>>>(vid, theta_w, theta_b, (float4*)v2cs);
  dist_kernel<<<dim3(256, T_), 256, 0, stream>>>((const float4*)v1cs, distG);
  select_kernel<<<dim3(NQ_, T_), 256, 0, stream>>>(distG, sel_n, sel_w, wsumv);
  agg_kernel<<<dim3(NQ_, T_), 256, 0, stream>>>((const float4*)v2cs, sel_n, sel_w, wsumv, Y);
  norm_kernel<<<(T_ * CI_ * HW_ + 255) / 256, 256, 0, stream>>>(Y);
}

// Round 8
// 386.941 us; speedup vs baseline: 1.3578x; 1.0217x over previous
//
#include <hip/hip_runtime.h>
#include <hip/hip_bf16.h>

#define T_ 4
#define C_ 64
#define H_ 128
#define W_ 128
#define CI_ 16
#define PS_ 7
#define NC_ 729       // 27*27 candidates per query
#define S0_ 4
#define KS_ 100
#define NQ_ 1024      // 32*32 queries per frame
#define SCALE_ 10.0f
#define HW_ (H_*W_)
#define RW_ 37        // region dim (float4); odd -> bank-quad rotation 5/row
#define LCAP_ 768

// ---------------- conv 3x3, 64->16, pad=1 (zero), chunk-major float4 output ----
// co split across 2 blocks (8 each); weights staged ONCE in LDS (coalesced
// identity copy), read per-(co,chunk) as 9 broadcast ds_read_b128.
__global__ __launch_bounds__(256) void conv3x3_kernel(
    const float* __restrict__ vid, const float* __restrict__ gw,
    const float* __restrict__ gb, float4* __restrict__ v1cs) {
  __shared__ float4 tileS[18 * 19];   // stride 19 (odd) to spread banks
  __shared__ float wls[8 * C_ * 9];   // identity copy of this co-group's weights
  const int tid = threadIdx.x;
  const int g = blockIdx.y;           // co-group: co = g*8 .. g*8+7
  const int t = blockIdx.z;
  const int ti0 = (blockIdx.x >> 3) * 16, tj0 = (blockIdx.x & 7) * 16;
  const int u = tid >> 4, v = tid & 15;

  // one-time coalesced weight stage: wls[m] = gw[g*8*64*9 + m]
  const float* gwb = gw + (size_t)g * 8 * C_ * 9;
  for (int m = tid; m < 8 * C_ * 9; m += 256) wls[m] = gwb[m];

  const int p0 = tid, p1 = tid + 256;
  const int uu0 = p0 / 18, vv0 = p0 - uu0 * 18;
  const int uu1 = p1 / 18, vv1 = p1 - uu1 * 18;
  const int gi0 = ti0 + uu0 - 1, gj0 = tj0 + vv0 - 1;
  const int gi1 = ti0 + uu1 - 1, gj1 = tj0 + vv1 - 1;
  const bool ok0 = (gi0 >= 0 && gi0 < H_ && gj0 >= 0 && gj0 < W_);
  const bool ok1 = (p1 < 324) && (gi1 >= 0 && gi1 < H_ && gj1 >= 0 && gj1 < W_);
  const int o0 = ok0 ? gi0 * W_ + gj0 : 0;
  const int o1 = ok1 ? gi1 * W_ + gj1 : 0;

  float4 pf0, pf1;
  {
    const float* vb = vid + ((size_t)(t * C_)) * HW_;
    pf0 = make_float4(0.f, 0.f, 0.f, 0.f);
    pf1 = make_float4(0.f, 0.f, 0.f, 0.f);
    if (ok0) { pf0.x = vb[o0]; pf0.y = vb[HW_ + o0]; pf0.z = vb[2 * HW_ + o0]; pf0.w = vb[3 * HW_ + o0]; }
    if (ok1) { pf1.x = vb[o1]; pf1.y = vb[HW_ + o1]; pf1.z = vb[2 * HW_ + o1]; pf1.w = vb[3 * HW_ + o1]; }
  }

  float acc[8];
#pragma unroll
  for (int co = 0; co < 8; ++co) acc[co] = gb[g * 8 + co];

#pragma unroll 1
  for (int cc = 0; cc < 16; ++cc) {
    __syncthreads();   // tile-read done (and, at cc=0, weight staging done)
    tileS[uu0 * 19 + vv0] = pf0;
    if (p1 < 324) tileS[uu1 * 19 + vv1] = pf1;
    __syncthreads();
    if (cc < 15) {
      const float* vb = vid + ((size_t)(t * C_ + (cc + 1) * 4)) * HW_;
      pf0 = make_float4(0.f, 0.f, 0.f, 0.f);
      pf1 = make_float4(0.f, 0.f, 0.f, 0.f);
      if (ok0) { pf0.x = vb[o0]; pf0.y = vb[HW_ + o0]; pf0.z = vb[2 * HW_ + o0]; pf0.w = vb[3 * HW_ + o0]; }
      if (ok1) { pf1.x = vb[o1]; pf1.y = vb[HW_ + o1]; pf1.z = vb[2 * HW_ + o1]; pf1.w = vb[3 * HW_ + o1]; }
    }
    float4 n[9];
#pragma unroll
    for (int ki = 0; ki < 3; ++ki)
#pragma unroll
      for (int kj = 0; kj < 3; ++kj)
        n[ki * 3 + kj] = tileS[(u + ki) * 19 + v + kj];
#pragma unroll
    for (int co = 0; co < 8; ++co) {
      // weights for (co, chunk cc): 36 contiguous floats = [c(4)][k(9)]
      const float4* wp = (const float4*)(wls + co * (C_ * 9) + cc * 36);
      float4 wq[9];
#pragma unroll
      for (int qq = 0; qq < 9; ++qq) wq[qq] = wp[qq];   // broadcast b128
      const float* wf = (const float*)wq;
#pragma unroll
      for (int k = 0; k < 9; ++k) {
        acc[co] = fmaf(wf[0 * 9 + k], n[k].x, acc[co]);
        acc[co] = fmaf(wf[1 * 9 + k], n[k].y, acc[co]);
        acc[co] = fmaf(wf[2 * 9 + k], n[k].z, acc[co]);
        acc[co] = fmaf(wf[3 * 9 + k], n[k].w, acc[co]);
      }
    }
  }
  const int pix = (ti0 + u) * W_ + tj0 + v;
  v1cs[((size_t)(g * 2) * T_ + t) * HW_ + pix]     = make_float4(acc[0], acc[1], acc[2], acc[3]);
  v1cs[((size_t)(g * 2 + 1) * T_ + t) * HW_ + pix] = make_float4(acc[4], acc[5], acc[6], acc[7]);
}

// ---------------- conv 1x1, 64->16, chunk-major float4 output ----------------
// cc split across 4 blocks -> 1024 blocks = 4/CU = 16 waves/CU.
__global__ __launch_bounds__(256) void conv1x1_kernel(
    const float* __restrict__ vid, const float* __restrict__ tw,
    const float* __restrict__ tb, float4* __restrict__ v2cs) {
  __shared__ float w[C_ * 4];   // w[c*4 + o] for this chunk's 4 outputs
  const int t = blockIdx.y, cc = blockIdx.z;
  for (int m = threadIdx.x; m < C_ * 4; m += 256) {
    int o = m & 3, c = m >> 2;
    w[m] = tw[(cc * 4 + o) * C_ + c];
  }
  __syncthreads();
  const int pix = blockIdx.x * 256 + threadIdx.x;
  float acc[4];
#pragma unroll
  for (int o = 0; o < 4; ++o) acc[o] = tb[cc * 4 + o];
  const float* vb = vid + ((size_t)t * C_) * HW_ + pix;
#pragma unroll 1
  for (int c0 = 0; c0 < C_; c0 += 8) {
    float x[8];
#pragma unroll
    for (int uu = 0; uu < 8; ++uu) x[uu] = vb[(size_t)(c0 + uu) * HW_];
#pragma unroll
    for (int uu = 0; uu < 8; ++uu)
#pragma unroll
      for (int o = 0; o < 4; ++o)
        acc[o] = fmaf(w[(c0 + uu) * 4 + o], x[uu], acc[o]);
  }
  v2cs[((size_t)cc * T_ + t) * HW_ + pix] = make_float4(acc[0], acc[1], acc[2], acc[3]);
}

// ---------------- dists: 2x2-query-tile region, wave=query, j=14/lane ------
__global__ __launch_bounds__(256) void dist_kernel(
    const float4* __restrict__ v1cs, float* __restrict__ distG) {
  __shared__ float4 Rs[RW_ * RW_];
  const int tid = threadIdx.x;
  const int t = blockIdx.y;
  const int qi0 = (blockIdx.x >> 4) * 8, qj0 = (blockIdx.x & 15) * 8;
  const int w = tid >> 6, lane = tid & 63;
  const int di = (w >> 1) * 4, dj = (w & 1) * 4;
  const int qi = qi0 + di, qj = qj0 + dj;
  const int a_lo = max(13 - qi, 0), b_lo = max(13 - qj, 0);
  const int ai = lane >> 1, bg = lane & 1;
  const bool active = ai < 27;
  const int a = min(a_lo + ai, 26);
  const int bs = bg ? 13 : b_lo;

  float acc[14];
#pragma unroll
  for (int j = 0; j < 14; ++j) acc[j] = 0.f;

#pragma unroll 1
  for (int cc = 0; cc < 4; ++cc) {
    __syncthreads();
    const float4* src = v1cs + ((size_t)cc * T_ + t) * HW_;
    for (int p = tid; p < RW_ * RW_; p += 256) {
      int uu = p / RW_, vv = p - uu * RW_;
      int row = min(max(qi0 - 13 + uu, 0), H_ - 1);
      int col = min(max(qj0 - 13 + vv, 0), W_ - 1);
      Rs[p] = src[row * W_ + col];
    }
    __syncthreads();
    if (active) {
#pragma unroll 1
      for (int r = 0; r < 7; ++r) {
        float4 qv[7];
        const float4* qrow = &Rs[(di + 13 + r) * RW_ + dj + 13];
#pragma unroll
        for (int s = 0; s < 7; ++s) qv[s] = qrow[s];
        const float4* crow = &Rs[(di + a + r) * RW_ + dj + bs];
#pragma unroll
        for (int y = 0; y < 20; ++y) {
          float4 vv = crow[y];
          const int s_lo = (y > 13) ? (y - 13) : 0;
          const int s_hi = (y < 6) ? y : 6;
#pragma unroll
          for (int s = s_lo; s <= s_hi; ++s) {
            float4 qq = qv[s];
            int j = y - s;
            acc[j] = fmaf(qq.x, vv.x, acc[j]);
            acc[j] = fmaf(qq.y, vv.y, acc[j]);
            acc[j] = fmaf(qq.z, vv.z, acc[j]);
            acc[j] = fmaf(qq.w, vv.w, acc[j]);
          }
        }
      }
    }
  }
  if (active) {
    const int q = ((qi >> 2) << 5) + (qj >> 2);
    float* out = distG + ((size_t)t * NQ_ + q) * NC_ + a * 27 + bs;
#pragma unroll
    for (int j = 0; j < 14; ++j) out[j] = acc[j];
  }
}

// ---------------- select: histogram top-100 + exact tie-break + softmax -----
__global__ __launch_bounds__(256) void select_kernel(
    const float* __restrict__ distG, int* __restrict__ sel_n,
    float* __restrict__ sel_w, float* __restrict__ wsum_out) {
  __shared__ float dist[NC_];
  __shared__ unsigned int ukey[NC_];
  __shared__ float red[256];
  __shared__ unsigned int hist[256];
  __shared__ int sfx[64];
  __shared__ int lk[LCAP_];
  __shared__ unsigned int lkey[LCAP_];
  __shared__ unsigned int scal[4];   // 0=beta 1=run 2=out cursor 3=list len

  const int tid = threadIdx.x;
  const int q = blockIdx.x, t = blockIdx.y;
  const int qi = (q >> 5) * S0_, qj = (q & 31) * S0_;
  const int a_lo = max(13 - qi, 0), b_lo = max(13 - qj, 0);
  const size_t base = ((size_t)t * NQ_ + q) * NC_;

  for (int h = tid; h < 256; h += 256) hist[h] = 0;
  if (tid == 0) { scal[2] = 0; scal[3] = 0; }
  for (int k = tid; k < NC_; k += 256) {
    int aa = k / 27, bb = k - aa * 27;
    int kk = max(aa, a_lo) * 27 + max(bb, b_lo);
    float d = distG[base + kk];
    dist[k] = d;
    unsigned int u = __float_as_uint(d);
    ukey[k] = u ^ (((unsigned int)((int)u >> 31)) | 0x80000000u);
  }
  __syncthreads();
  float lmax = -INFINITY;
  for (int k = tid; k < NC_; k += 256) lmax = fmaxf(lmax, dist[k]);
  red[tid] = lmax;
  __syncthreads();
  for (int off = 128; off > 0; off >>= 1) {
    if (tid < off) red[tid] = fmaxf(red[tid], red[tid + off]);
    __syncthreads();
  }
  const float dmax = red[0];
  __syncthreads();
  for (int k = tid; k < NC_; k += 256) atomicAdd(&hist[ukey[k] >> 24], 1u);
  __syncthreads();
  if (tid < 64)
    sfx[tid] = (int)(hist[tid * 4] + hist[tid * 4 + 1] + hist[tid * 4 + 2] + hist[tid * 4 + 3]);
  __syncthreads();
  for (int off = 1; off < 64; off <<= 1) {
    int v = 0;
    if (tid < 64 && tid + off < 64) v = sfx[tid + off];
    __syncthreads();
    if (tid < 64) sfx[tid] += v;
    __syncthreads();
  }
  if (tid < 64) {
    int s4 = (int)(hist[tid * 4] + hist[tid * 4 + 1] + hist[tid * 4 + 2] + hist[tid * 4 + 3]);
    int above = sfx[tid] - s4;
    if (above < KS_ && sfx[tid] >= KS_) {
      int run = above;
#pragma unroll
      for (int bb = 3; bb >= 0; --bb) {
        int h = (int)hist[tid * 4 + bb];
        if (run + h >= KS_) { scal[0] = (unsigned int)(tid * 4 + bb); scal[1] = (unsigned int)run; break; }
        run += h;
      }
    }
  }
  __syncthreads();
  const unsigned int beta = scal[0];
  const int run = (int)scal[1];
  const size_t outb = ((size_t)t * NQ_ + q) * KS_;
  float lsum = 0.f;
  for (int k = tid; k < NC_; k += 256) {
    unsigned int key = ukey[k];
    unsigned int bin = key >> 24;
    if (bin > beta) {
      unsigned int slot = atomicAdd(&scal[2], 1u);
      int aa = k / 27, bb = k - aa * 27;
      int ni = min(max(qi + aa - 13, 0), H_ - 1);
      int nj = min(max(qj + bb - 13, 0), W_ - 1);
      float wv = __expf(SCALE_ * (dist[k] - dmax));
      sel_n[outb + slot] = (ni << 7) | nj;
      sel_w[outb + slot] = wv;
      lsum += wv;
    } else if (bin == beta) {
      unsigned int pos = atomicAdd(&scal[3], 1u);
      if (pos < LCAP_) { lk[pos] = k; lkey[pos] = key; }
    }
  }
  __syncthreads();
  const int L = min((int)scal[3], LCAP_);
  for (int i = tid; i < L; i += 256) {
    unsigned int key = lkey[i];
    int k = lk[i];
    int cnt = run;
    for (int m = 0; m < L; ++m)
      cnt += (int)((lkey[m] > key) || (lkey[m] == key && lk[m] < k));
    if (cnt < KS_) {
      unsigned int slot = atomicAdd(&scal[2], 1u);
      int aa = k / 27, bb = k - aa * 27;
      int ni = min(max(qi + aa - 13, 0), H_ - 1);
      int nj = min(max(qj + bb - 13, 0), W_ - 1);
      float wv = __expf(SCALE_ * (dist[k] - dmax));
      sel_n[outb + slot] = (ni << 7) | nj;
      sel_w[outb + slot] = wv;
      lsum += wv;
    }
  }
  __syncthreads();
  red[tid] = lsum;
  __syncthreads();
  for (int off = 128; off > 0; off >>= 1) {
    if (tid < off) red[tid] += red[tid + off];
    __syncthreads();
  }
  if (tid == 0) wsum_out[t * NQ_ + q] = red[0];
}

// ---------------- weighted aggregation + fold (direct L2 gather) ------------
__global__ __launch_bounds__(256) void agg_kernel(
    const float4* __restrict__ v2cs, const int* __restrict__ sel_n,
    const float* __restrict__ sel_w, const float* __restrict__ wsum,
    float* __restrict__ Y) {
  __shared__ int s_ni[KS_], s_nj[KS_];
  __shared__ float s_w[KS_];
  const int tid = threadIdx.x;
  const int q = blockIdx.x, t = blockIdx.y;
  const int qi = (q >> 5) * S0_, qj = (q & 31) * S0_;
  const size_t base = ((size_t)t * NQ_ + q) * KS_;
  if (tid < KS_) {
    int n = sel_n[base + tid];
    s_ni[tid] = n >> 7;
    s_nj[tid] = n & 127;
    s_w[tid] = sel_w[base + tid] / wsum[t * NQ_ + q];
  }
  __syncthreads();
  const int cc = tid >> 6, lane = tid & 63;
  if (lane >= 49) return;
  const int r = lane / 7, s = lane - r * 7;
  const float4* src = v2cs + ((size_t)cc * T_ + t) * HW_;
  float4 acc = make_float4(0.f, 0.f, 0.f, 0.f);
#pragma unroll 4
  for (int k = 0; k < KS_; ++k) {
    int ri = min(s_ni[k] + r, H_ - 1);
    int ci = min(s_nj[k] + s, W_ - 1);
    float4 v = src[ri * W_ + ci];
    float w = s_w[k];
    acc.x = fmaf(w, v.x, acc.x);
    acc.y = fmaf(w, v.y, acc.y);
    acc.z = fmaf(w, v.z, acc.z);
    acc.w = fmaf(w, v.w, acc.w);
  }
  const int oi = min(qi + r, H_ - 1), oj = min(qj + s, W_ - 1);
  float* yb = Y + (((size_t)t * CI_ + cc * 4) * H_ + oi) * W_ + oj;
  atomicAdd(yb, acc.x);
  atomicAdd(yb + HW_, acc.y);
  atomicAdd(yb + 2 * HW_, acc.z);
  atomicAdd(yb + 3 * HW_, acc.w);
}

// ---------------- normalize by analytic fold counts -------------------------
__device__ __forceinline__ int cov_axis(int x) {
  int c = 0;
#pragma unroll
  for (int r = 0; r < 7; ++r) {
    if (x < H_ - 1) {
      int qb = x - r;
      c += (qb >= 0 && (qb & 3) == 0) ? 1 : 0;
    } else {
      c += (r >= 3) ? 1 : 0;
    }
  }
  return c;
}

__global__ void norm_kernel(float* __restrict__ Y) {
  int idx = blockIdx.x * blockDim.x + threadIdx.x;
  if (idx >= T_ * CI_ * HW_) return;
  int p = idx & (HW_ - 1);
  float z = (float)(cov_axis(p >> 7) * cov_axis(p & 127));
  Y[idx] /= z;
}

extern "C" void kernel_launch(void* const* d_in, const int* in_sizes, int n_in,
                              void* d_out, int out_size, void* d_ws, size_t ws_size,
                              hipStream_t stream) {
  const float* vid     = (const float*)d_in[0];
  const float* g_w     = (const float*)d_in[1];
  const float* g_b     = (const float*)d_in[2];
  const float* theta_w = (const float*)d_in[3];
  const float* theta_b = (const float*)d_in[4];
  float* Y = (float*)d_out;

  // workspace (floats): v1cs | v2cs | distG | sel_n | sel_w | wsum  (~24 MB)
  float* v1cs  = (float*)d_ws;
  float* v2cs  = v1cs + (size_t)4 * T_ * HW_ * 4;              // 1048576
  float* distG = v2cs + (size_t)4 * T_ * HW_ * 4;              // 1048576
  int*   sel_n = (int*)(distG + (size_t)T_ * NQ_ * NC_);       // 2985984
  float* sel_w = (float*)(sel_n + (size_t)T_ * NQ_ * KS_);     // 409600
  float* wsumv = sel_w + (size_t)T_ * NQ_ * KS_;               // 409600

  hipMemsetAsync(Y, 0, (size_t)out_size * sizeof(float), stream);

  conv3x3_kernel<<<dim3(64, 2, T_), 256, 0, stream>>>(vid, g_w, g_b, (float4*)v1cs);
  conv1x1_kernel<<<dim3(HW_ / 256, T_, 4), 256, 0, stream>>>(vid, theta_w, theta_b, (float4*)v2cs);
  dist_kernel<<<dim3(256, T_), 256, 0, stream>>>((const float4*)v1cs, distG);
  select_kernel<<<dim3(NQ_, T_), 256, 0, stream>>>(distG, sel_n, sel_w, wsumv);
  agg_kernel<<<dim3(NQ_, T_), 256, 0, stream>>>((const float4*)v2cs, sel_n, sel_w, wsumv, Y);
  norm_kernel<<<(T_ * CI_ * HW_ + 255) / 256, 256, 0, stream>>>(Y);
}

// Round 9
// 314.147 us; speedup vs baseline: 1.6724x; 1.2317x over previous
//
#include <hip/hip_runtime.h>
#include <hip/hip_bf16.h>

#define T_ 4
#define C_ 64
#define H_ 128
#define W_ 128
#define CI_ 16
#define PS_ 7
#define NC_ 729       // 27*27 candidates per query
#define S0_ 4
#define KS_ 100
#define NQ_ 1024      // 32*32 queries per frame
#define SCALE_ 10.0f
#define HW_ (H_*W_)
#define RW_ 45        // 4x4-tile region dim (float4); 45%8=5 -> bank rotation
#define LCAP_ 768

// ---------------- conv 3x3, 64->16, zero-barrier direct conv ----------------
// Grid (64, 4, T): co-group g of 4 = output chunk g. 4 blocks/CU, no barriers
// after weight stage; 9-neighbor predicated loads come from L1.
// wls layout [c][k][co] -> 4 contiguous weights per (c,k) => v_pk_fma pairs.
__global__ __launch_bounds__(256) void conv3x3_kernel(
    const float* __restrict__ vid, const float* __restrict__ gw,
    const float* __restrict__ gb, float4* __restrict__ v1cs) {
  __shared__ float wls[C_ * 9 * 4];
  const int tid = threadIdx.x;
  const int g = blockIdx.y, t = blockIdx.z;
  for (int m = tid; m < C_ * 9 * 4; m += 256) {
    int co = m & 3, ck = m >> 2;           // ck = c*9+k
    wls[m] = gw[((size_t)(g * 4 + co) * C_) * 9 + ck];
  }
  __syncthreads();
  const int ti0 = (blockIdx.x >> 3) * 16, tj0 = (blockIdx.x & 7) * 16;
  const int u = tid >> 4, v = tid & 15;
  const int i = ti0 + u, j = tj0 + v;

  bool ok[9];
  int off[9];
#pragma unroll
  for (int ki = 0; ki < 3; ++ki)
#pragma unroll
    for (int kj = 0; kj < 3; ++kj) {
      int ii = i + ki - 1, jj = j + kj - 1;
      bool o = (ii >= 0) && (ii < H_) && (jj >= 0) && (jj < W_);
      ok[ki * 3 + kj] = o;
      off[ki * 3 + kj] = o ? ii * W_ + jj : 0;
    }

  float acc[4];
#pragma unroll
  for (int co = 0; co < 4; ++co) acc[co] = gb[g * 4 + co];

  const float* vb = vid + ((size_t)t * C_) * HW_;
#pragma unroll 1
  for (int c0 = 0; c0 < C_; c0 += 2) {
    float n0[9], n1[9];
    const float* p0 = vb + (size_t)c0 * HW_;
    const float* p1 = p0 + HW_;
#pragma unroll
    for (int k = 0; k < 9; ++k) n0[k] = ok[k] ? p0[off[k]] : 0.f;
#pragma unroll
    for (int k = 0; k < 9; ++k) n1[k] = ok[k] ? p1[off[k]] : 0.f;
#pragma unroll
    for (int k = 0; k < 9; ++k) {
      const float* w0 = &wls[(c0 * 9 + k) * 4];
#pragma unroll
      for (int co = 0; co < 4; ++co) acc[co] = fmaf(w0[co], n0[k], acc[co]);
    }
#pragma unroll
    for (int k = 0; k < 9; ++k) {
      const float* w1 = &wls[((c0 + 1) * 9 + k) * 4];
#pragma unroll
      for (int co = 0; co < 4; ++co) acc[co] = fmaf(w1[co], n1[k], acc[co]);
    }
  }
  v1cs[((size_t)g * T_ + t) * HW_ + i * W_ + j] =
      make_float4(acc[0], acc[1], acc[2], acc[3]);
}

// ---------------- conv 1x1, 64->16, chunk-major float4 output ----------------
__global__ __launch_bounds__(256) void conv1x1_kernel(
    const float* __restrict__ vid, const float* __restrict__ tw,
    const float* __restrict__ tb, float4* __restrict__ v2cs) {
  __shared__ float w[C_ * 4];
  const int t = blockIdx.y, cc = blockIdx.z;
  for (int m = threadIdx.x; m < C_ * 4; m += 256) {
    int o = m & 3, c = m >> 2;
    w[m] = tw[(cc * 4 + o) * C_ + c];
  }
  __syncthreads();
  const int pix = blockIdx.x * 256 + threadIdx.x;
  float acc[4];
#pragma unroll
  for (int o = 0; o < 4; ++o) acc[o] = tb[cc * 4 + o];
  const float* vb = vid + ((size_t)t * C_) * HW_ + pix;
#pragma unroll 1
  for (int c0 = 0; c0 < C_; c0 += 8) {
    float x[8];
#pragma unroll
    for (int uu = 0; uu < 8; ++uu) x[uu] = vb[(size_t)(c0 + uu) * HW_];
#pragma unroll
    for (int uu = 0; uu < 8; ++uu)
#pragma unroll
      for (int o = 0; o < 4; ++o)
        acc[o] = fmaf(w[(c0 + uu) * 4 + o], x[uu], acc[o]);
  }
  v2cs[((size_t)cc * T_ + t) * HW_ + pix] = make_float4(acc[0], acc[1], acc[2], acc[3]);
}

// ---------------- dists: 4x4-query-tile region, wave=query, j=14/lane ------
// 1024-thread block (16 waves = 16 queries), 45x45 float4 region, grid 256
// blocks = exactly 1/CU. Staging per query: 2025/16 float4 loads.
__global__ __launch_bounds__(1024) void dist_kernel(
    const float4* __restrict__ v1cs, float* __restrict__ distG) {
  __shared__ float4 Rs[RW_ * RW_];
  const int tid = threadIdx.x;
  const int t = blockIdx.y;
  const int qi0 = (blockIdx.x >> 3) * 16, qj0 = (blockIdx.x & 7) * 16;
  const int w = tid >> 6, lane = tid & 63;
  const int di = (w >> 2) * 4, dj = (w & 3) * 4;
  const int qi = qi0 + di, qj = qj0 + dj;
  const int a_lo = max(13 - qi, 0), b_lo = max(13 - qj, 0);
  const int ai = lane >> 1, bg = lane & 1;
  const bool active = ai < 27;
  const int a = min(a_lo + ai, 26);
  const int bs = bg ? 13 : b_lo;

  float acc[14];
#pragma unroll
  for (int j = 0; j < 14; ++j) acc[j] = 0.f;

#pragma unroll 1
  for (int cc = 0; cc < 4; ++cc) {
    __syncthreads();
    const float4* src = v1cs + ((size_t)cc * T_ + t) * HW_;
    for (int p = tid; p < RW_ * RW_; p += 1024) {
      int uu = p / RW_, vv = p - uu * RW_;
      int row = min(max(qi0 - 13 + uu, 0), H_ - 1);
      int col = min(max(qj0 - 13 + vv, 0), W_ - 1);
      Rs[p] = src[row * W_ + col];
    }
    __syncthreads();
    if (active) {
#pragma unroll 1
      for (int r = 0; r < 7; ++r) {
        float4 qv[7];
        const float4* qrow = &Rs[(di + 13 + r) * RW_ + dj + 13];
#pragma unroll
        for (int s = 0; s < 7; ++s) qv[s] = qrow[s];
        const float4* crow = &Rs[(di + a + r) * RW_ + dj + bs];
#pragma unroll
        for (int y = 0; y < 20; ++y) {
          float4 vv = crow[y];
          const int s_lo = (y > 13) ? (y - 13) : 0;
          const int s_hi = (y < 6) ? y : 6;
#pragma unroll
          for (int s = s_lo; s <= s_hi; ++s) {
            float4 qq = qv[s];
            int j = y - s;
            acc[j] = fmaf(qq.x, vv.x, acc[j]);
            acc[j] = fmaf(qq.y, vv.y, acc[j]);
            acc[j] = fmaf(qq.z, vv.z, acc[j]);
            acc[j] = fmaf(qq.w, vv.w, acc[j]);
          }
        }
      }
    }
  }
  if (active) {
    const int q = ((qi >> 2) << 5) + (qj >> 2);
    float* out = distG + ((size_t)t * NQ_ + q) * NC_ + a * 27 + bs;
#pragma unroll
    for (int j = 0; j < 14; ++j) out[j] = acc[j];
  }
}

// ---------------- select: 2-level radix top-100 + exact tie-break + softmax -
__global__ __launch_bounds__(256) void select_kernel(
    const float* __restrict__ distG, int* __restrict__ sel_n,
    float* __restrict__ sel_w, float* __restrict__ wsum_out) {
  __shared__ float dist[NC_];
  __shared__ unsigned int ukey[NC_];
  __shared__ float red[256];
  __shared__ unsigned int hist[256];
  __shared__ int sfx[64];
  __shared__ int lk[LCAP_];
  __shared__ unsigned int lkey[LCAP_];
  __shared__ unsigned int scal[6];   // 0=beta 1=run 2=cursor 3=listlen 4=beta2 5=run2

  const int tid = threadIdx.x;
  const int q = blockIdx.x, t = blockIdx.y;
  const int qi = (q >> 5) * S0_, qj = (q & 31) * S0_;
  const int a_lo = max(13 - qi, 0), b_lo = max(13 - qj, 0);
  const size_t base = ((size_t)t * NQ_ + q) * NC_;

  for (int h = tid; h < 256; h += 256) hist[h] = 0;
  if (tid == 0) { scal[2] = 0; scal[3] = 0; }
  for (int k = tid; k < NC_; k += 256) {
    int aa = k / 27, bb = k - aa * 27;
    int kk = max(aa, a_lo) * 27 + max(bb, b_lo);
    float d = distG[base + kk];
    dist[k] = d;
    unsigned int u = __float_as_uint(d);
    ukey[k] = u ^ (((unsigned int)((int)u >> 31)) | 0x80000000u);
  }
  __syncthreads();
  float lmax = -INFINITY;
  for (int k = tid; k < NC_; k += 256) lmax = fmaxf(lmax, dist[k]);
  red[tid] = lmax;
  __syncthreads();
  for (int off = 128; off > 0; off >>= 1) {
    if (tid < off) red[tid] = fmaxf(red[tid], red[tid + off]);
    __syncthreads();
  }
  const float dmax = red[0];
  __syncthreads();
  // ---- level 1: top byte ----
  for (int k = tid; k < NC_; k += 256) atomicAdd(&hist[ukey[k] >> 24], 1u);
  __syncthreads();
  if (tid < 64)
    sfx[tid] = (int)(hist[tid * 4] + hist[tid * 4 + 1] + hist[tid * 4 + 2] + hist[tid * 4 + 3]);
  __syncthreads();
  for (int off = 1; off < 64; off <<= 1) {
    int v = 0;
    if (tid < 64 && tid + off < 64) v = sfx[tid + off];
    __syncthreads();
    if (tid < 64) sfx[tid] += v;
    __syncthreads();
  }
  if (tid < 64) {
    int s4 = (int)(hist[tid * 4] + hist[tid * 4 + 1] + hist[tid * 4 + 2] + hist[tid * 4 + 3]);
    int above = sfx[tid] - s4;
    if (above < KS_ && sfx[tid] >= KS_) {
      int run = above;
#pragma unroll
      for (int bb = 3; bb >= 0; --bb) {
        int h = (int)hist[tid * 4 + bb];
        if (run + h >= KS_) { scal[0] = (unsigned int)(tid * 4 + bb); scal[1] = (unsigned int)run; break; }
        run += h;
      }
    }
  }
  __syncthreads();
  const unsigned int beta = scal[0];
  const int run = (int)scal[1];
  __syncthreads();
  // ---- level 2: second byte within bin beta ----
  for (int h = tid; h < 256; h += 256) hist[h] = 0;
  __syncthreads();
  for (int k = tid; k < NC_; k += 256)
    if ((ukey[k] >> 24) == beta) atomicAdd(&hist[(ukey[k] >> 16) & 0xFFu], 1u);
  __syncthreads();
  if (tid < 64)
    sfx[tid] = (int)(hist[tid * 4] + hist[tid * 4 + 1] + hist[tid * 4 + 2] + hist[tid * 4 + 3]);
  __syncthreads();
  for (int off = 1; off < 64; off <<= 1) {
    int v = 0;
    if (tid < 64 && tid + off < 64) v = sfx[tid + off];
    __syncthreads();
    if (tid < 64) sfx[tid] += v;
    __syncthreads();
  }
  if (tid < 64) {
    int s4 = (int)(hist[tid * 4] + hist[tid * 4 + 1] + hist[tid * 4 + 2] + hist[tid * 4 + 3]);
    int above = run + sfx[tid] - s4;
    if (above < KS_ && run + sfx[tid] >= KS_) {
      int r2 = above;
#pragma unroll
      for (int bb = 3; bb >= 0; --bb) {
        int h = (int)hist[tid * 4 + bb];
        if (r2 + h >= KS_) { scal[4] = (unsigned int)(tid * 4 + bb); scal[5] = (unsigned int)r2; break; }
        r2 += h;
      }
    }
  }
  __syncthreads();
  const unsigned int beta2 = scal[4];
  const int run2 = (int)scal[5];
  const size_t outb = ((size_t)t * NQ_ + q) * KS_;
  float lsum = 0.f;
  for (int k = tid; k < NC_; k += 256) {
    unsigned int key = ukey[k];
    unsigned int bin = key >> 24;
    bool sel = false, bdry = false;
    if (bin > beta) sel = true;
    else if (bin == beta) {
      unsigned int b2 = (key >> 16) & 0xFFu;
      if (b2 > beta2) sel = true;
      else if (b2 == beta2) bdry = true;
    }
    if (sel) {
      unsigned int slot = atomicAdd(&scal[2], 1u);
      int aa = k / 27, bb = k - aa * 27;
      int ni = min(max(qi + aa - 13, 0), H_ - 1);
      int nj = min(max(qj + bb - 13, 0), W_ - 1);
      float wv = __expf(SCALE_ * (dist[k] - dmax));
      sel_n[outb + slot] = (ni << 7) | nj;
      sel_w[outb + slot] = wv;
      lsum += wv;
    } else if (bdry) {
      unsigned int pos = atomicAdd(&scal[3], 1u);
      if (pos < LCAP_) { lk[pos] = k; lkey[pos] = key; }
    }
  }
  __syncthreads();
  const int L = min((int)scal[3], LCAP_);
  for (int i = tid; i < L; i += 256) {
    unsigned int key = lkey[i];
    int k = lk[i];
    int cnt = run2;
    for (int m = 0; m < L; ++m)
      cnt += (int)((lkey[m] > key) || (lkey[m] == key && lk[m] < k));
    if (cnt < KS_) {
      unsigned int slot = atomicAdd(&scal[2], 1u);
      int aa = k / 27, bb = k - aa * 27;
      int ni = min(max(qi + aa - 13, 0), H_ - 1);
      int nj = min(max(qj + bb - 13, 0), W_ - 1);
      float wv = __expf(SCALE_ * (dist[k] - dmax));
      sel_n[outb + slot] = (ni << 7) | nj;
      sel_w[outb + slot] = wv;
      lsum += wv;
    }
  }
  __syncthreads();
  red[tid] = lsum;
  __syncthreads();
  for (int off = 128; off > 0; off >>= 1) {
    if (tid < off) red[tid] += red[tid + off];
    __syncthreads();
  }
  if (tid == 0) wsum_out[t * NQ_ + q] = red[0];
}

// ---------------- weighted aggregation + fold (direct L2 gather) ------------
__global__ __launch_bounds__(256) void agg_kernel(
    const float4* __restrict__ v2cs, const int* __restrict__ sel_n,
    const float* __restrict__ sel_w, const float* __restrict__ wsum,
    float* __restrict__ Y) {
  __shared__ int s_ni[KS_], s_nj[KS_];
  __shared__ float s_w[KS_];
  const int tid = threadIdx.x;
  const int q = blockIdx.x, t = blockIdx.y;
  const int qi = (q >> 5) * S0_, qj = (q & 31) * S0_;
  const size_t base = ((size_t)t * NQ_ + q) * KS_;
  if (tid < KS_) {
    int n = sel_n[base + tid];
    s_ni[tid] = n >> 7;
    s_nj[tid] = n & 127;
    s_w[tid] = sel_w[base + tid] / wsum[t * NQ_ + q];
  }
  __syncthreads();
  const int cc = tid >> 6, lane = tid & 63;
  if (lane >= 49) return;
  const int r = lane / 7, s = lane - r * 7;
  const float4* src = v2cs + ((size_t)cc * T_ + t) * HW_;
  float4 acc = make_float4(0.f, 0.f, 0.f, 0.f);
#pragma unroll 4
  for (int k = 0; k < KS_; ++k) {
    int ri = min(s_ni[k] + r, H_ - 1);
    int ci = min(s_nj[k] + s, W_ - 1);
    float4 v = src[ri * W_ + ci];
    float w = s_w[k];
    acc.x = fmaf(w, v.x, acc.x);
    acc.y = fmaf(w, v.y, acc.y);
    acc.z = fmaf(w, v.z, acc.z);
    acc.w = fmaf(w, v.w, acc.w);
  }
  const int oi = min(qi + r, H_ - 1), oj = min(qj + s, W_ - 1);
  float* yb = Y + (((size_t)t * CI_ + cc * 4) * H_ + oi) * W_ + oj;
  atomicAdd(yb, acc.x);
  atomicAdd(yb + HW_, acc.y);
  atomicAdd(yb + 2 * HW_, acc.z);
  atomicAdd(yb + 3 * HW_, acc.w);
}

// ---------------- normalize by analytic fold counts -------------------------
__device__ __forceinline__ int cov_axis(int x) {
  int c = 0;
#pragma unroll
  for (int r = 0; r < 7; ++r) {
    if (x < H_ - 1) {
      int qb = x - r;
      c += (qb >= 0 && (qb & 3) == 0) ? 1 : 0;
    } else {
      c += (r >= 3) ? 1 : 0;
    }
  }
  return c;
}

__global__ void norm_kernel(float* __restrict__ Y) {
  int idx = blockIdx.x * blockDim.x + threadIdx.x;
  if (idx >= T_ * CI_ * HW_) return;
  int p = idx & (HW_ - 1);
  float z = (float)(cov_axis(p >> 7) * cov_axis(p & 127));
  Y[idx] /= z;
}

extern "C" void kernel_launch(void* const* d_in, const int* in_sizes, int n_in,
                              void* d_out, int out_size, void* d_ws, size_t ws_size,
                              hipStream_t stream) {
  const float* vid     = (const float*)d_in[0];
  const float* g_w     = (const float*)d_in[1];
  const float* g_b     = (const float*)d_in[2];
  const float* theta_w = (const float*)d_in[3];
  const float* theta_b = (const float*)d_in[4];
  float* Y = (float*)d_out;

  // workspace (floats): v1cs | v2cs | distG | sel_n | sel_w | wsum  (~24 MB)
  float* v1cs  = (float*)d_ws;
  float* v2cs  = v1cs + (size_t)4 * T_ * HW_ * 4;              // 1048576
  float* distG = v2cs + (size_t)4 * T_ * HW_ * 4;              // 1048576
  int*   sel_n = (int*)(distG + (size_t)T_ * NQ_ * NC_);       // 2985984
  float* sel_w = (float*)(sel_n + (size_t)T_ * NQ_ * KS_);     // 409600
  float* wsumv = sel_w + (size_t)T_ * NQ_ * KS_;               // 409600

  hipMemsetAsync(Y, 0, (size_t)out_size * sizeof(float), stream);

  conv3x3_kernel<<<dim3(64, 4, T_), 256, 0, stream>>>(vid, g_w, g_b, (float4*)v1cs);
  conv1x1_kernel<<<dim3(HW_ / 256, T_, 4), 256, 0, stream>>>(vid, theta_w, theta_b, (float4*)v2cs);
  dist_kernel<<<dim3(64, T_), 1024, 0, stream>>>((const float4*)v1cs, distG);
  select_kernel<<<dim3(NQ_, T_), 256, 0, stream>>>(distG, sel_n, sel_w, wsumv);
  agg_kernel<<<dim3(NQ_, T_), 256, 0, stream>>>((const float4*)v2cs, sel_n, sel_w, wsumv, Y);
  norm_kernel<<<(T_ * CI_ * HW_ + 255) / 256, 256, 0, stream>>>(Y);
}